// Round 1
// 1326.343 us; speedup vs baseline: 2.4114x; 2.4114x over previous
//
#include <hip/hip_runtime.h>
#include <hip/hip_bf16.h>

typedef __hip_bfloat16 bf16;

#define N_NODES 50000
#define N_EDGES 400000
#define IN_DIM  256
#define EDGE_F  64
#define OUT_DIM 32
#define EDGE_OUT 64
#define NHEADS  8
#define HD      256   // NHEADS*OUT_DIM
#define ALPHA   0.2f
#define BN_EPS  1e-5f

__device__ __forceinline__ float b2f(bf16 v){ return __bfloat162float(v); }
__device__ __forceinline__ bf16  f2b(float v){ return __float2bfloat16(v); }
__device__ __forceinline__ float lrelu(float x){ return x > 0.f ? x : ALPHA*x; }
__device__ __forceinline__ unsigned fenc(float f){ unsigned u=__float_as_uint(f); return (u&0x80000000u)? ~u : (u|0x80000000u); }
__device__ __forceinline__ float fdec(unsigned k){ return (k&0x80000000u)? __uint_as_float(k&0x7fffffffu) : __uint_as_float(~k); }

// dtype-adaptive load/store: F32=true -> fp32 buffer, else bf16 buffer
template<bool F32> __device__ __forceinline__ float LD(const void* p, long i){
  if constexpr (F32) return ((const float*)p)[i];
  else               return b2f(((const bf16*)p)[i]);
}
template<bool F32> __device__ __forceinline__ void ST(void* p, long i, float v){
  if constexpr (F32) ((float*)p)[i] = v;
  else               ((bf16*)p)[i] = f2b(v);
}
// edge-section base inside d_out: skip N*HD elements of the flag-selected dtype
template<bool F32> __device__ __forceinline__ void* ESEC(void* out){
  return (char*)out + (size_t)N_NODES*HD*(F32?4:2);
}

// ---------------- MFMA fragment helpers (16x16x32 bf16) ----------------
typedef __attribute__((ext_vector_type(8))) short bf16x8;
typedef __attribute__((ext_vector_type(4))) float f32x4;

union PackU { uint4 u; bf16x8 v; };
__device__ __forceinline__ bf16x8 as_frag(uint4 w){ PackU p; p.u = w; return p.v; }
__device__ __forceinline__ bf16x8 zero_frag(){ PackU p; p.u = make_uint4(0,0,0,0); return p.v; }

#define MFMA16(a,b,c) __builtin_amdgcn_mfma_f32_16x16x32_bf16(a,b,c,0,0,0)

// split 8 f32 into hi (truncated-top-16) and lo (bf16 of exact remainder):
// float(hi)+float(lo) == v to ~2^-16 relative -> f32-equivalent A operand
__device__ __forceinline__ void split8(float4 a, float4 b, bf16x8& hi, bf16x8& lo){
  float v[8] = {a.x,a.y,a.z,a.w,b.x,b.y,b.z,b.w};
  unsigned hu[4], lu[4];
  #pragma unroll
  for(int i=0;i<4;i++){
    unsigned u0 = __float_as_uint(v[2*i]);
    unsigned u1 = __float_as_uint(v[2*i+1]);
    unsigned h0 = u0 & 0xffff0000u, h1 = u1 & 0xffff0000u;
    hu[i] = (u0>>16) | h1;
    float l0 = v[2*i]   - __uint_as_float(h0);
    float l1 = v[2*i+1] - __uint_as_float(h1);
    union { bf16 h; unsigned short s; } c0, c1; c0.h = f2b(l0); c1.h = f2b(l1);
    lu[i] = (unsigned)c0.s | ((unsigned)c1.s << 16);
  }
  PackU H,L;
  H.u = make_uint4(hu[0],hu[1],hu[2],hu[3]);
  L.u = make_uint4(lu[0],lu[1],lu[2],lu[3]);
  hi = H.v; lo = L.v;
}

// load 8 consecutive elements (16B/32B) -> hi/lo A-fragment regs
template<bool F32> __device__ __forceinline__ void load_split(const void* p, long off, bf16x8& hi, bf16x8& lo){
  if constexpr(F32){
    const float* f = (const float*)p + off;
    float4 a = *(const float4*)f;
    float4 b = *(const float4*)(f+4);
    split8(a,b,hi,lo);
  } else {
    hi = as_frag(*(const uint4*)((const bf16*)p + off));
    lo = zero_frag();
  }
}

// ---- K0: input-dtype detector (fp32 viewed as u16 shows absurd bf16 exponents) ----
__global__ __launch_bounds__(256) void k_detect(const unsigned short* __restrict__ u,
                                                int* __restrict__ flag){
  __shared__ int cnt;
  if(threadIdx.x==0) cnt=0;
  __syncthreads();
  int local=0;
  for(int i=threadIdx.x;i<8192;i+=256){
    int e = (u[i]>>7)&0xFF;
    if(e>=200) local++;               // |x| >= 2^73: impossible for N(0,1) data
  }
  atomicAdd(&cnt, local);
  __syncthreads();
  if(threadIdx.x==0) *flag = (cnt>64) ? 1 : 0;   // 1 => buffers are fp32
}

// ---------------- K1: ft = node_inputs @ fc_w -> d_out node section ----------------
template<bool F32> __device__ void node_proj_body(const void* x, const void* w,
                                                  void* ft, float* sx){
  int n0 = blockIdx.x * 8;
  int t  = threadIdx.x;
  #pragma unroll
  for(int r=0;r<8;r++) sx[t*8+r] = LD<F32>(x,(long)(n0+r)*IN_DIM + t);
  __syncthreads();
  float acc[8] = {0,0,0,0,0,0,0,0};
  #pragma unroll 4
  for(int k=0;k<IN_DIM;k++){
    float wv = LD<F32>(w,(long)k*HD + t);
    const float4 u0 = *(const float4*)&sx[k*8];
    const float4 u1 = *(const float4*)&sx[k*8+4];
    acc[0] += u0.x*wv; acc[1] += u0.y*wv; acc[2] += u0.z*wv; acc[3] += u0.w*wv;
    acc[4] += u1.x*wv; acc[5] += u1.y*wv; acc[6] += u1.z*wv; acc[7] += u1.w*wv;
  }
  #pragma unroll
  for(int r=0;r<8;r++) ST<F32>(ft,(long)(n0+r)*HD + t, acc[r]);
}
__global__ __launch_bounds__(256) void k_node_proj(const void* x, const void* w,
                                                   void* ft, const int* flag){
  extern __shared__ float smemf[];
  if(*flag) node_proj_body<true >(x,w,ft,smemf);
  else      node_proj_body<false>(x,w,ft,smemf);
}

// ---------------- K2: a1/a2 per-(node,head) dots ----------------
template<bool F32> __device__ void attn_body(const void* ft, const void* al, const void* ar,
                                             float* a1, float* a2){
  int gid = blockIdx.x*8 + (threadIdx.x>>5);
  int d   = threadIdx.x & 31;
  int h   = gid & 7;
  float v  = LD<F32>(ft,(long)gid*OUT_DIM + d);
  float s1 = v * LD<F32>(al, h*OUT_DIM + d);
  float s2 = v * LD<F32>(ar, h*OUT_DIM + d);
  for(int o=16;o>0;o>>=1){ s1 += __shfl_down(s1,o,32); s2 += __shfl_down(s2,o,32); }
  if(d==0){ a1[gid]=s1; a2[gid]=s2; }
}
__global__ __launch_bounds__(256) void k_attn(const void* ft, const void* al, const void* ar,
                                              float* a1, float* a2, const int* flag){
  if(*flag) attn_body<true >(ft,al,ar,a1,a2);
  else      attn_body<false>(ft,al,ar,a1,a2);
}

// ---------------- K3: edge-attn MLP + lrelu + segment-max ----------------
template<bool F32> __device__ void edge_attn_body(const void* ein, const void* w1, const void* b1,
                                                  const void* w2, const void* b2,
                                                  const float* a1, const float* a2,
                                                  const int* src, const int* dst,
                                                  float* a_edge, unsigned* amax, float* sm){
  float* sw1 = sm;            // 2048
  float* sw2 = sw1 + 2048;    // 256
  float* sb1 = sw2 + 256;     // 32
  float* sb2 = sb1 + 32;      // 8
  float* se  = sb2 + 8;       // 8*64
  float* st  = se  + 512;     // 8*32
  int t = threadIdx.x;
  #pragma unroll
  for(int i=0;i<8;i++) sw1[i*256+t] = LD<F32>(w1, i*256+t);
  sw2[t] = LD<F32>(w2, t);
  if(t<OUT_DIM) sb1[t]=LD<F32>(b1,t);
  if(t<NHEADS)  sb2[t]=LD<F32>(b2,t);
  int e0 = blockIdx.x*8;
  #pragma unroll
  for(int i=0;i<2;i++){ int idx=i*256+t; se[idx] = LD<F32>(ein,(long)e0*EDGE_F + idx); }
  __syncthreads();
  int r = t>>5, j = t&31;
  float acc = sb1[j];
  #pragma unroll 4
  for(int k=0;k<EDGE_F;k++) acc += se[r*64+k]*sw1[k*OUT_DIM+j];
  st[r*32+j] = lrelu(acc);
  __syncthreads();
  if(t<64){
    int rr = t>>3, h = t&7;
    float s = sb2[h];
    #pragma unroll
    for(int jj=0;jj<OUT_DIM;jj++) s += st[rr*32+jj]*sw2[jj*NHEADS+h];
    int e = e0+rr;
    int sv = src[e], dv = dst[e];
    float av = lrelu(a1[sv*NHEADS+h] + a2[dv*NHEADS+h] + s);   // TEMP==1
    a_edge[(long)e*NHEADS+h] = av;
    atomicMax(&amax[dv*NHEADS+h], fenc(av));
  }
}
__global__ __launch_bounds__(256) void k_edge_attn(const void* ein, const void* w1, const void* b1,
                                                   const void* w2, const void* b2,
                                                   const float* a1, const float* a2,
                                                   const int* src, const int* dst,
                                                   float* a_edge, unsigned* amax, const int* flag){
  extern __shared__ float smemf[];
  if(*flag) edge_attn_body<true >(ein,w1,b1,w2,b2,a1,a2,src,dst,a_edge,amax,smemf);
  else      edge_attn_body<false>(ein,w1,b1,w2,b2,a1,a2,src,dst,a_edge,amax,smemf);
}

// ---------------- K4: softmax numerators, z, weighted aggregation ----------------
template<bool F32> __device__ void soft_agg_body(const void* ft, const float* a_edge,
                                                 const unsigned* amax,
                                                 const int* src, const int* dst,
                                                 float* z, float* agg, float* sav){
  int w = threadIdx.x>>6, lane = threadIdx.x&63;
  int e = blockIdx.x*4 + w;
  int sv = src[e], dv = dst[e];
  if(lane < NHEADS){
    float av = __expf(a_edge[(long)e*NHEADS+lane] - fdec(amax[dv*NHEADS+lane]));
    unsafeAtomicAdd(&z[dv*NHEADS+lane], av);
    sav[w*NHEADS+lane] = av;
  }
  __syncthreads();
  long fbase = (long)sv*HD;
  float* aggp = agg + (size_t)dv*HD;
  #pragma unroll
  for(int q=0;q<4;q++){
    int j = lane + 64*q;
    unsafeAtomicAdd(&aggp[j], LD<F32>(ft, fbase+j)*sav[w*NHEADS+(j>>5)]);
  }
}
__global__ __launch_bounds__(256) void k_soft_agg(const void* ft, const float* a_edge,
                                                  const unsigned* amax,
                                                  const int* src, const int* dst,
                                                  float* z, float* agg, const int* flag){
  __shared__ float sav[4*NHEADS];
  if(*flag) soft_agg_body<true >(ft,a_edge,amax,src,dst,z,agg,sav);
  else      soft_agg_body<false>(ft,a_edge,amax,src,dst,z,agg,sav);
}

// ---------------- K5: residual + lrelu -> pre-BN x into d_out node section; stats ----------------
template<bool F32> __device__ void node_stage_body(const float* agg, const float* z,
                                                   const void* xin, void* xout, double* dstats){
  int t = threadIdx.x;
  double s=0.0, q=0.0;
  for(int n=blockIdx.x; n<N_NODES; n+=gridDim.x){
    float zz = z[n*NHEADS + (t>>5)];
    float zs = (zz==0.f) ? 1.f : zz;
    float x  = lrelu(agg[(long)n*HD+t]/zs + LD<F32>(xin,(long)n*HD+t));
    ST<F32>(xout,(long)n*HD+t, x);
    s += x; q += (double)x*(double)x;
  }
  unsafeAtomicAdd(&dstats[t],    s);
  unsafeAtomicAdd(&dstats[HD+t], q);
}
__global__ __launch_bounds__(256) void k_node_stage(const float* agg, const float* z,
                                                    const void* xin, void* xout,
                                                    double* dstats, const int* flag){
  if(*flag) node_stage_body<true >(agg,z,xin,xout,dstats);
  else      node_stage_body<false>(agg,z,xin,xout,dstats);
}

// ---------------- BN params from double sums ----------------
template<bool F32> __device__ void bn_params_body(const double* dstats, const void* g,
                                                  const void* b, float* scsh, int C, double invM){
  int t = threadIdx.x;
  if(t>=C) return;
  double mu  = dstats[t]*invM;
  double var = dstats[C+t]*invM - mu*mu;
  if(var < 0.0) var = 0.0;
  float sc = LD<F32>(g,t) * rsqrtf((float)var + BN_EPS);
  scsh[t]   = sc;
  scsh[C+t] = LD<F32>(b,t) - (float)mu*sc;
}
__global__ void k_bn_params(const double* dstats, const void* g, const void* b,
                            float* scsh, int C, double invM, const int* flag){
  if(*flag) bn_params_body<true >(dstats,g,b,scsh,C,invM);
  else      bn_params_body<false>(dstats,g,b,scsh,C,invM);
}

// ---------------- K6: node BN apply, in place on d_out node section ----------------
template<bool F32> __device__ void node_apply_body(void* x, const float* scsh){
  int t = threadIdx.x;
  float sc = scsh[t], sh = scsh[HD+t];
  for(long i=(long)blockIdx.x*256+t; i<(long)N_NODES*HD; i+=(long)gridDim.x*256){
    ST<F32>(x, i, fmaf(LD<F32>(x,i), sc, sh));
  }
}
__global__ __launch_bounds__(256) void k_node_apply(void* x, const float* scsh, const int* flag){
  if(*flag) node_apply_body<true >(x,scsh);
  else      node_apply_body<false>(x,scsh);
}

// ---------------- K6b: pack eu weights into MFMA B-fragment order (bf16) ----------------
// layout per matrix: frag f = (kstep*4 + ntile); element ((f*64 + lane)*8 + j)
//   holds W[kstep*32 + (lane>>4)*8 + j][ntile*16 + (lane&15)]
// sections (bf16 element offsets): wn @0 (32768), we @32768 (4096), wf @36864 (8192)
template<bool F32> __device__ void pack_body(const void* wn, const void* we, const void* wf,
                                             unsigned short* out){
  int i = blockIdx.x*256 + threadIdx.x;
  if(i >= 45056) return;
  const void* srcp; int idx;
  if(i < 32768){ srcp = wn; idx = i; }
  else if(i < 36864){ srcp = we; idx = i - 32768; }
  else { srcp = wf; idx = i - 36864; }
  int j = idx & 7, lane = (idx>>3)&63, nt = (idx>>9)&3, ks = idx>>11;
  int k = ks*32 + ((lane>>4)<<3) + j;
  int n = (nt<<4) + (lane&15);
  union { bf16 h; unsigned short s; } u;
  u.h = f2b(LD<F32>(srcp, (long)k*EDGE_OUT + n));
  out[i] = u.s;
}
__global__ __launch_bounds__(256) void k_pack_w(const void* wn, const void* we, const void* wf,
                                                unsigned short* out, const int* flag){
  if(*flag) pack_body<true >(wn,we,wf,out);
  else      pack_body<false>(wn,we,wf,out);
}

// ---------------- K7: fused edge update via MFMA -> pre-BN edge into d_out edge section ----
// 4 waves/block, each wave owns 16 edges x 64 outputs.
// node_f = lrelu([x[src]|x[dst]] @ Wn)  (K=512), edge_f = lrelu(e_in @ We) (K=64),
// out    = lrelu(concat @ Wf + e_in)    (K=128).
// A operands: f32 activations split hi/lo bf16 (f32-equivalent); B: bf16 weights
// (same precision scheme as the previous VALU kernel that passed at absmax 0.031).
#define LROW 132   // padded LDS row stride (f32) for the 16x128 per-wave intermediate

template<bool F32>
__device__ void edge_update_body(const void* nodeb, const void* edge_in,
                                 const int* src, const int* dst,
                                 const unsigned short* wpack,
                                 void* d_out, float* lds){
  void* edge_x = ESEC<F32>(d_out);
  const uint4* wn4 = (const uint4*)wpack;   // 4096 frags-uint4
  const uint4* we4 = wn4 + 4096;            // 512
  const uint4* wf4 = wn4 + 4608;            // 1024
  int wid   = threadIdx.x >> 6;
  int lane  = threadIdx.x & 63;
  int row16 = lane & 15;
  int kgrp  = lane >> 4;
  int e0  = blockIdx.x*64 + wid*16;
  int e_a = e0 + row16;
  int nsrc = src[e_a], ndst = dst[e_a];
  float* myl = lds + wid*(16*LROW);

  f32x4 acc_h[4], acc_l[4];
  #pragma unroll
  for(int t=0;t<4;t++){ acc_h[t]=(f32x4){0.f,0.f,0.f,0.f}; acc_l[t]=(f32x4){0.f,0.f,0.f,0.f}; }

  // ---- node GEMM: K = 512 (src rows 0..255 -> Wn[0:256], dst -> Wn[256:512]) ----
  #pragma unroll
  for(int half=0; half<2; half++){
    long rowbase = (long)(half ? ndst : nsrc) * HD;
    #pragma unroll 2
    for(int ks=0; ks<8; ks++){
      bf16x8 ah, al;
      load_split<F32>(nodeb, rowbase + ks*32 + kgrp*8, ah, al);
      const uint4* wb = wn4 + (size_t)((half*8 + ks)*4)*64 + lane;
      #pragma unroll
      for(int nt=0; nt<4; nt++){
        bf16x8 bfr = as_frag(wb[nt*64]);
        acc_h[nt] = MFMA16(ah, bfr, acc_h[nt]);
        if constexpr(F32) acc_l[nt] = MFMA16(al, bfr, acc_l[nt]);
      }
    }
  }
  #pragma unroll
  for(int nt=0; nt<4; nt++)
    #pragma unroll
    for(int j=0;j<4;j++)
      myl[(kgrp*4+j)*LROW + nt*16 + row16] = lrelu(acc_h[nt][j] + acc_l[nt][j]);

  // ---- edge-feature GEMM: K = 64 ----
  #pragma unroll
  for(int t=0;t<4;t++){ acc_h[t]=(f32x4){0.f,0.f,0.f,0.f}; acc_l[t]=(f32x4){0.f,0.f,0.f,0.f}; }
  long ebase = (long)e_a * EDGE_F;
  #pragma unroll
  for(int ks=0; ks<2; ks++){
    bf16x8 ah, al;
    load_split<F32>(edge_in, ebase + ks*32 + kgrp*8, ah, al);
    const uint4* wb = we4 + (size_t)(ks*4)*64 + lane;
    #pragma unroll
    for(int nt=0; nt<4; nt++){
      bf16x8 bfr = as_frag(wb[nt*64]);
      acc_h[nt] = MFMA16(ah, bfr, acc_h[nt]);
      if constexpr(F32) acc_l[nt] = MFMA16(al, bfr, acc_l[nt]);
    }
  }
  #pragma unroll
  for(int nt=0; nt<4; nt++)
    #pragma unroll
    for(int j=0;j<4;j++)
      myl[(kgrp*4+j)*LROW + 64 + nt*16 + row16] = lrelu(acc_h[nt][j] + acc_l[nt][j]);

  __syncthreads();   // LDS C-layout -> A-layout redistribution barrier

  // ---- final GEMM: K = 128 from LDS, + residual, lrelu, store ----
  #pragma unroll
  for(int t=0;t<4;t++){ acc_h[t]=(f32x4){0.f,0.f,0.f,0.f}; acc_l[t]=(f32x4){0.f,0.f,0.f,0.f}; }
  #pragma unroll
  for(int ks=0; ks<4; ks++){
    const float* ap = myl + row16*LROW + ks*32 + kgrp*8;
    float4 a0 = *(const float4*)ap;
    float4 a1 = *(const float4*)(ap+4);
    bf16x8 ah, al; split8(a0,a1,ah,al);
    const uint4* wb = wf4 + (size_t)(ks*4)*64 + lane;
    #pragma unroll
    for(int nt=0; nt<4; nt++){
      bf16x8 bfr = as_frag(wb[nt*64]);
      acc_h[nt] = MFMA16(ah, bfr, acc_h[nt]);
      acc_l[nt] = MFMA16(al, bfr, acc_l[nt]);
    }
  }
  #pragma unroll
  for(int nt=0; nt<4; nt++)
    #pragma unroll
    for(int j=0;j<4;j++){
      long e = e0 + kgrp*4 + j;
      int  c = nt*16 + row16;
      float res = LD<F32>(edge_in, e*EDGE_OUT + c);
      ST<F32>(edge_x, e*EDGE_OUT + c, lrelu(acc_h[nt][j] + acc_l[nt][j] + res));
    }
}
__global__ __launch_bounds__(256) void k_edge_update(const void* nodeb, const void* edge_in,
                                                     const int* src, const int* dst,
                                                     const unsigned short* wpack,
                                                     void* d_out, const int* flag){
  extern __shared__ float smemf[];
  if(*flag) edge_update_body<true >(nodeb,edge_in,src,dst,wpack,d_out,smemf);
  else      edge_update_body<false>(nodeb,edge_in,src,dst,wpack,d_out,smemf);
}

// ---------------- K8: edge column stats ----------------
template<bool F32> __device__ void edge_stats_body(void* d_out, double* dstats, double* sm){
  const void* ex = ESEC<F32>(d_out);
  double* ls = sm; double* lq = sm+256;
  int t = threadIdx.x;
  int c = t & 63, r0 = t >> 6;
  double s=0.0, q=0.0;
  for(long i=(long)(blockIdx.x*4 + r0)*64 + c; i < (long)N_EDGES*EDGE_OUT; i += (long)gridDim.x*4*64){
    float x = LD<F32>(ex, i);
    s += x; q += (double)x*(double)x;
  }
  ls[t]=s; lq[t]=q;
  __syncthreads();
  if(t<64){
    double ss = ls[t]+ls[t+64]+ls[t+128]+ls[t+192];
    double qq = lq[t]+lq[t+64]+lq[t+128]+lq[t+192];
    unsafeAtomicAdd(&dstats[t], ss);
    unsafeAtomicAdd(&dstats[64+t], qq);
  }
}
__global__ __launch_bounds__(256) void k_edge_stats(void* d_out, double* dstats, const int* flag){
  extern __shared__ double smemd[];
  if(*flag) edge_stats_body<true >(d_out,dstats,smemd);
  else      edge_stats_body<false>(d_out,dstats,smemd);
}

// ---------------- K9: edge BN apply, in place on d_out edge section ----------------
template<bool F32> __device__ void edge_apply_body(void* d_out, const float* scsh){
  void* ex = ESEC<F32>(d_out);
  int t = threadIdx.x;
  int c = t & 63;
  float sc = scsh[c], sh = scsh[64+c];
  for(long i=(long)blockIdx.x*256+t; i<(long)N_EDGES*EDGE_OUT; i+=(long)gridDim.x*256){
    ST<F32>(ex, i, fmaf(LD<F32>(ex,i), sc, sh));
  }
}
__global__ __launch_bounds__(256) void k_edge_apply(void* d_out, const float* scsh, const int* flag){
  if(*flag) edge_apply_body<true >(d_out,scsh);
  else      edge_apply_body<false>(d_out,scsh);
}

extern "C" void kernel_launch(void* const* d_in, const int* in_sizes, int n_in,
                              void* d_out, int out_size, void* d_ws, size_t ws_size,
                              hipStream_t stream){
  const void* node_in    = d_in[0];
  const void* edge_in    = d_in[1];
  const void* fc_w       = d_in[2];
  const void* attn_l     = d_in[3];
  const void* attn_r     = d_in[4];
  const void* ae_w1      = d_in[5];
  const void* ae_b1      = d_in[6];
  const void* ae_w2      = d_in[7];
  const void* ae_b2      = d_in[8];
  const void* bn_n_g     = d_in[9];
  const void* bn_n_b     = d_in[10];
  const void* eu_node_w  = d_in[11];
  const void* eu_edge_w  = d_in[12];
  const void* eu_final_w = d_in[13];
  const void* bn_e_g     = d_in[14];
  const void* bn_e_b     = d_in[15];
  const int*  src        = (const int*)d_in[16];
  const int*  dst        = (const int*)d_in[17];

  // ---- workspace (~70.4 MB) ----
  char* base = (char*)d_ws;
  double*   dstats_n = (double*)base;                 // 512 dbl
  double*   dstats_e = (double*)(base + 4096);        // 128 dbl
  float*    scsh_n   = (float*)(base + 5120);         // 512 f
  float*    scsh_e   = (float*)(base + 7168);         // 128 f
  int*      flag     = (int*)(base + 7680);
  char*     big      = base + 8192;
  float*    aggb     = (float*)big;                   // N*HD f32 = 51.2MB
  float*    a_edge   = (float*)(big + 51200000);      // E*8  f32 = 12.8MB
  float*    a1       = (float*)(big + 64000000);      // N*8
  float*    a2       = (float*)(big + 65600000);      // N*8
  unsigned* amax     = (unsigned*)(big + 67200000);   // N*8
  float*    zb       = (float*)(big + 68800000);      // N*8  (ends ~70.4MB)
  // packed eu weights (90KB, bf16 fragments) — reuses a_edge region, which is
  // dead after k_soft_agg and before k_pack_w runs.
  unsigned short* wpack = (unsigned short*)(big + 51200000);

  hipMemsetAsync(dstats_n, 0, 640*sizeof(double), stream);
  hipMemsetAsync(aggb, 0, (size_t)N_NODES*HD*sizeof(float), stream);
  hipMemsetAsync(amax, 0, (size_t)N_NODES*NHEADS*2*sizeof(unsigned), stream); // amax + zb

  k_detect<<<1, 256, 0, stream>>>((const unsigned short*)node_in, flag);
  k_node_proj<<<N_NODES/8, 256, 8192, stream>>>(node_in, fc_w, d_out, flag);
  k_attn<<<N_NODES*NHEADS/8, 256, 0, stream>>>(d_out, attn_l, attn_r, a1, a2, flag);
  k_edge_attn<<<N_EDGES/8, 256, 12448, stream>>>(edge_in, ae_w1, ae_b1, ae_w2, ae_b2,
                                                 a1, a2, src, dst, a_edge, amax, flag);
  k_soft_agg<<<N_EDGES/4, 256, 0, stream>>>(d_out, a_edge, amax, src, dst, zb, aggb, flag);
  k_node_stage<<<512, 256, 0, stream>>>(aggb, zb, node_in, d_out, dstats_n, flag);
  k_bn_params<<<1, 256, 0, stream>>>(dstats_n, bn_n_g, bn_n_b, scsh_n, HD, 1.0/N_NODES, flag);
  k_node_apply<<<2048, 256, 0, stream>>>(d_out, scsh_n, flag);
  k_pack_w<<<176, 256, 0, stream>>>(eu_node_w, eu_edge_w, eu_final_w, wpack, flag);
  k_edge_update<<<N_EDGES/64, 256, 4*16*LROW*4, stream>>>(d_out, edge_in, src, dst,
                                                          wpack, d_out, flag);
  k_edge_stats<<<512, 256, 4096, stream>>>(d_out, dstats_e, flag);
  k_bn_params<<<1, 256, 0, stream>>>(dstats_e, bn_e_g, bn_e_b, scsh_e, EDGE_OUT, 1.0/N_EDGES, flag);
  k_edge_apply<<<2048, 256, 0, stream>>>(d_out, scsh_e, flag);
  (void)ws_size; (void)out_size; (void)n_in; (void)in_sizes;
}

// Round 3
// 1091.848 us; speedup vs baseline: 2.9293x; 1.2148x over previous
//
#include <hip/hip_runtime.h>
#include <hip/hip_bf16.h>

typedef __hip_bfloat16 bf16;

#define N_NODES 50000
#define N_EDGES 400000
#define IN_DIM  256
#define EDGE_F  64
#define OUT_DIM 32
#define EDGE_OUT 64
#define NHEADS  8
#define HD      256   // NHEADS*OUT_DIM
#define ALPHA   0.2f
#define BN_EPS  1e-5f

#define NBINS 50432   // 197*256, >= N_NODES+1
#define NBLK  197

__device__ __forceinline__ float b2f(bf16 v){ return __bfloat162float(v); }
__device__ __forceinline__ bf16  f2b(float v){ return __float2bfloat16(v); }
__device__ __forceinline__ float lrelu(float x){ return x > 0.f ? x : ALPHA*x; }
__device__ __forceinline__ unsigned fenc(float f){ unsigned u=__float_as_uint(f); return (u&0x80000000u)? ~u : (u|0x80000000u); }
__device__ __forceinline__ float fdec(unsigned k){ return (k&0x80000000u)? __uint_as_float(k&0x7fffffffu) : __uint_as_float(~k); }

// dtype-adaptive load/store: F32=true -> fp32 buffer, else bf16 buffer
template<bool F32> __device__ __forceinline__ float LD(const void* p, long i){
  if constexpr (F32) return ((const float*)p)[i];
  else               return b2f(((const bf16*)p)[i]);
}
template<bool F32> __device__ __forceinline__ void ST(void* p, long i, float v){
  if constexpr (F32) ((float*)p)[i] = v;
  else               ((bf16*)p)[i] = f2b(v);
}
// edge-section base inside d_out: skip N*HD elements of the flag-selected dtype
template<bool F32> __device__ __forceinline__ void* ESEC(void* out){
  return (char*)out + (size_t)N_NODES*HD*(F32?4:2);
}

// ---------------- MFMA fragment helpers (16x16x32 bf16) ----------------
typedef __attribute__((ext_vector_type(8))) short bf16x8;
typedef __attribute__((ext_vector_type(4))) float f32x4;

union PackU { uint4 u; bf16x8 v; };
__device__ __forceinline__ bf16x8 as_frag(uint4 w){ PackU p; p.u = w; return p.v; }
__device__ __forceinline__ bf16x8 zero_frag(){ PackU p; p.u = make_uint4(0,0,0,0); return p.v; }

#define MFMA16(a,b,c) __builtin_amdgcn_mfma_f32_16x16x32_bf16(a,b,c,0,0,0)

// split 8 f32 into hi (truncated-top-16) and lo (bf16 of exact remainder)
__device__ __forceinline__ void split8(float4 a, float4 b, bf16x8& hi, bf16x8& lo){
  float v[8] = {a.x,a.y,a.z,a.w,b.x,b.y,b.z,b.w};
  unsigned hu[4], lu[4];
  #pragma unroll
  for(int i=0;i<4;i++){
    unsigned u0 = __float_as_uint(v[2*i]);
    unsigned u1 = __float_as_uint(v[2*i+1]);
    unsigned h0 = u0 & 0xffff0000u, h1 = u1 & 0xffff0000u;
    hu[i] = (u0>>16) | h1;
    float l0 = v[2*i]   - __uint_as_float(h0);
    float l1 = v[2*i+1] - __uint_as_float(h1);
    union { bf16 h; unsigned short s; } c0, c1; c0.h = f2b(l0); c1.h = f2b(l1);
    lu[i] = (unsigned)c0.s | ((unsigned)c1.s << 16);
  }
  PackU H,L;
  H.u = make_uint4(hu[0],hu[1],hu[2],hu[3]);
  L.u = make_uint4(lu[0],lu[1],lu[2],lu[3]);
  hi = H.v; lo = L.v;
}

// load 8 consecutive elements -> hi/lo A-fragment regs
template<bool F32> __device__ __forceinline__ void load_split(const void* p, long off, bf16x8& hi, bf16x8& lo){
  if constexpr(F32){
    const float* f = (const float*)p + off;
    float4 a = *(const float4*)f;
    float4 b = *(const float4*)(f+4);
    split8(a,b,hi,lo);
  } else {
    hi = as_frag(*(const uint4*)((const bf16*)p + off));
    lo = zero_frag();
  }
}

// ---- K0: input-dtype detector ----
__global__ __launch_bounds__(256) void k_detect(const unsigned short* __restrict__ u,
                                                int* __restrict__ flag){
  __shared__ int cnt;
  if(threadIdx.x==0) cnt=0;
  __syncthreads();
  int local=0;
  for(int i=threadIdx.x;i<8192;i+=256){
    int e = (u[i]>>7)&0xFF;
    if(e>=200) local++;
  }
  atomicAdd(&cnt, local);
  __syncthreads();
  if(threadIdx.x==0) *flag = (cnt>64) ? 1 : 0;   // 1 => buffers are fp32
}

// ---------------- CSR build: histogram + 2-level scan (dst only) ----------------
__global__ __launch_bounds__(256) void k_hist(const int* __restrict__ dst, int* __restrict__ cnt){
  int e = blockIdx.x*256 + threadIdx.x;
  if(e < N_EDGES){
    unsigned d = (unsigned)dst[e];
    if(d < N_NODES) atomicAdd(&cnt[d], 1);
  }
}
__global__ __launch_bounds__(256) void k_scan1(const int* __restrict__ cnt, int* __restrict__ rs,
                                               int* __restrict__ btot){
  __shared__ int s[256];
  int t = threadIdx.x; int i = blockIdx.x*256 + t;
  int v = cnt[i]; s[t] = v; __syncthreads();
  for(int off=1; off<256; off<<=1){
    int x = (t>=off) ? s[t-off] : 0; __syncthreads();
    s[t] += x; __syncthreads();
  }
  rs[i] = s[t] - v;
  if(t==255) btot[blockIdx.x] = s[t];
}
__global__ __launch_bounds__(256) void k_scan2(const int* __restrict__ btot, int* __restrict__ bsum){
  __shared__ int s[256];
  int t = threadIdx.x;
  int v = (t<NBLK) ? btot[t] : 0; s[t] = v; __syncthreads();
  for(int off=1; off<256; off<<=1){
    int x = (t>=off) ? s[t-off] : 0; __syncthreads();
    s[t] += x; __syncthreads();
  }
  if(t<NBLK) bsum[t] = s[t] - v;
}
__global__ __launch_bounds__(256) void k_scan3(int* __restrict__ rs, const int* __restrict__ bsum,
                                               int* __restrict__ cursor){
  int i = blockIdx.x*256 + threadIdx.x;
  int r = rs[i] + bsum[blockIdx.x];
  rs[i] = r; cursor[i] = r;
}

// ---------------- K6b: generic weight pack into MFMA B-fragment order (bf16) ----------
// element ((ks*NT+nt)*64+lane)*8+j  <-  W[ks*32 + (lane>>4)*8 + j][nt*16 + (lane&15)]
template<bool F32> __device__ void pack_body(const void* wn, const void* we, const void* wf,
                                             unsigned short* out){
  int i = blockIdx.x*256 + threadIdx.x;
  if(i >= 45056) return;
  const void* srcp; int idx;
  if(i < 32768){ srcp = wn; idx = i; }
  else if(i < 36864){ srcp = we; idx = i - 32768; }
  else { srcp = wf; idx = i - 36864; }
  int j = idx & 7, lane = (idx>>3)&63, nt = (idx>>9)&3, ks = idx>>11;
  int k = ks*32 + ((lane>>4)<<3) + j;
  int n = (nt<<4) + (lane&15);
  union { bf16 h; unsigned short s; } u;
  u.h = f2b(LD<F32>(srcp, (long)k*EDGE_OUT + n));
  out[i] = u.s;
}
__global__ __launch_bounds__(256) void k_pack_w(const void* wn, const void* we, const void* wf,
                                                unsigned short* out, const int* flag){
  if(*flag) pack_body<true >(wn,we,wf,out);
  else      pack_body<false>(wn,we,wf,out);
}
// fc_w pack: K=256, Nout=256 (NT=16), 65536 elems
template<bool F32> __device__ void pack_fc_body(const void* w, unsigned short* out){
  int i = blockIdx.x*256 + threadIdx.x;
  int j = i&7, lane = (i>>3)&63, nt = (i>>9)&15, ks = i>>13;
  int k = ks*32 + ((lane>>4)<<3) + j;
  int n = (nt<<4) + (lane&15);
  union { bf16 h; unsigned short s; } u;
  u.h = f2b(LD<F32>(w, (long)k*HD + n));
  out[i] = u.s;
}
__global__ __launch_bounds__(256) void k_pack_fc(const void* w, unsigned short* out, const int* flag){
  if(*flag) pack_fc_body<true >(w,out);
  else      pack_fc_body<false>(w,out);
}

// ---------------- K1: ft = node_inputs @ fc_w via MFMA -> ftb (f32 workspace) -------
// 4 waves/block, each wave: 16 rows x 256 cols.
template<bool F32> __device__ void nproj_body(const void* x, const unsigned short* wpf, float* ft){
  const uint4* w4 = (const uint4*)wpf;
  int wid = threadIdx.x>>6, lane = threadIdx.x&63;
  int row16 = lane&15, kgrp = lane>>4;
  int r0 = blockIdx.x*64 + wid*16;
  long arow = r0 + row16; if(arow >= N_NODES) arow = N_NODES-1;
  f32x4 acc[16];
  #pragma unroll
  for(int nt=0;nt<16;nt++) acc[nt] = (f32x4){0.f,0.f,0.f,0.f};
  #pragma unroll 2
  for(int ks=0;ks<8;ks++){
    bf16x8 ah, al;
    load_split<F32>(x, arow*IN_DIM + ks*32 + kgrp*8, ah, al);
    const uint4* wb = w4 + (size_t)(ks*16)*64 + lane;
    #pragma unroll
    for(int nt=0;nt<16;nt++){
      bf16x8 b = as_frag(wb[nt*64]);
      if constexpr(F32) acc[nt] = MFMA16(al, b, acc[nt]);
      acc[nt] = MFMA16(ah, b, acc[nt]);
    }
  }
  #pragma unroll
  for(int nt=0;nt<16;nt++)
    #pragma unroll
    for(int j=0;j<4;j++){
      int r = r0 + kgrp*4 + j;
      if(r < N_NODES) ft[(long)r*HD + nt*16 + row16] = acc[nt][j];
    }
}
__global__ __launch_bounds__(256) void k_node_proj(const void* x, const unsigned short* wpf,
                                                   float* ft, const int* flag){
  if(*flag) nproj_body<true >(x,wpf,ft);
  else      nproj_body<false>(x,wpf,ft);
}

// ---------------- K2: a1/a2 per-(node,head) dots (ft is f32) ----------------
template<bool F32> __device__ void attn_body(const float* ft, const void* al, const void* ar,
                                             float* a1, float* a2){
  int gid = blockIdx.x*8 + (threadIdx.x>>5);
  int d   = threadIdx.x & 31;
  int h   = gid & 7;
  float v  = ft[(long)gid*OUT_DIM + d];
  float s1 = v * LD<F32>(al, h*OUT_DIM + d);
  float s2 = v * LD<F32>(ar, h*OUT_DIM + d);
  for(int o=16;o>0;o>>=1){ s1 += __shfl_down(s1,o,32); s2 += __shfl_down(s2,o,32); }
  if(d==0){ a1[gid]=s1; a2[gid]=s2; }
}
__global__ __launch_bounds__(256) void k_attn(const float* ft, const void* al, const void* ar,
                                              float* a1, float* a2, const int* flag){
  if(*flag) attn_body<true >(ft,al,ar,a1,a2);
  else      attn_body<false>(ft,al,ar,a1,a2);
}

// ---------------- K3: edge-attn MLP + lrelu + segment-max + CSR slot write ----------
template<bool F32> __device__ void edge_attn_body(const void* ein, const void* w1, const void* b1,
                                                  const void* w2, const void* b2,
                                                  const float* a1, const float* a2,
                                                  const int* src, const int* dst,
                                                  int* cursor, unsigned short* psrc,
                                                  float* a_edge, unsigned* amax, float* sm){
  float* sw1 = sm;            // 2048
  float* sw2 = sw1 + 2048;    // 256
  float* sb1 = sw2 + 256;     // 32
  float* sb2 = sb1 + 32;      // 8
  float* se  = sb2 + 8;       // 8*64
  float* st  = se  + 512;     // 8*32
  int t = threadIdx.x;
  #pragma unroll
  for(int i=0;i<8;i++) sw1[i*256+t] = LD<F32>(w1, i*256+t);
  sw2[t] = LD<F32>(w2, t);
  if(t<OUT_DIM) sb1[t]=LD<F32>(b1,t);
  if(t<NHEADS)  sb2[t]=LD<F32>(b2,t);
  int e0 = blockIdx.x*8;
  #pragma unroll
  for(int i=0;i<2;i++){ int idx=i*256+t; se[idx] = LD<F32>(ein,(long)e0*EDGE_F + idx); }
  __syncthreads();
  int r = t>>5, j = t&31;
  float acc = sb1[j];
  #pragma unroll 4
  for(int k=0;k<EDGE_F;k++) acc += se[r*64+k]*sw1[k*OUT_DIM+j];
  st[r*32+j] = lrelu(acc);
  __syncthreads();
  if(t<64){
    int rr = t>>3, h = t&7;
    float s = sb2[h];
    #pragma unroll
    for(int jj=0;jj<OUT_DIM;jj++) s += st[rr*32+jj]*sw2[jj*NHEADS+h];
    int e = e0+rr;
    int sv = src[e], dv = dst[e];
    float av = lrelu(a1[sv*NHEADS+h] + a2[dv*NHEADS+h] + s);   // TEMP==1
    int pos = 0;
    if(h==0) pos = atomicAdd(&cursor[dv], 1);
    pos = __shfl(pos, rr*8, 64);
    a_edge[(long)pos*NHEADS + h] = av;
    if(h==0) psrc[pos] = (unsigned short)sv;
    atomicMax(&amax[dv*NHEADS+h], fenc(av));
  }
}
__global__ __launch_bounds__(256) void k_edge_attn(const void* ein, const void* w1, const void* b1,
                                                   const void* w2, const void* b2,
                                                   const float* a1, const float* a2,
                                                   const int* src, const int* dst,
                                                   int* cursor, unsigned short* psrc,
                                                   float* a_edge, unsigned* amax, const int* flag){
  extern __shared__ float smemf[];
  if(*flag) edge_attn_body<true >(ein,w1,b1,w2,b2,a1,a2,src,dst,cursor,psrc,a_edge,amax,smemf);
  else      edge_attn_body<false>(ein,w1,b1,w2,b2,a1,a2,src,dst,cursor,psrc,a_edge,amax,smemf);
}

// ---------------- K4: fused CSR aggregation + softmax + residual + lrelu + BN stats --
// one wave per node; a_edge/psrc are in CSR (dst-sorted) order -> no atomics.
template<bool F32> __device__ void agg_body(const int* rs, const unsigned short* psrc,
                                            const float* a_edge, const unsigned* amax,
                                            const float* ft, const void* xin, void* xout,
                                            double* dstats, double* sm){
  int wid = threadIdx.x>>6, lane = threadIdx.x&63;
  int gw = blockIdx.x*4 + wid, nw = gridDim.x*4;
  int h0 = lane>>5;
  double s4[4]={0,0,0,0}, q4[4]={0,0,0,0};
  for(int n=gw; n<N_NODES; n+=nw){
    int b0 = rs[n], b1 = rs[n+1];
    if(b1 > N_EDGES) b1 = N_EDGES;
    if(b0 > b1) b0 = b1;
    float m = (lane<8) ? fdec(amax[n*NHEADS+lane]) : 0.f;
    float zl = 0.f;
    float acc[4] = {0,0,0,0};
    for(int i=b0;i<b1;++i){
      float av = 0.f;
      if(lane<8){ av = __expf(a_edge[(long)i*NHEADS+lane] - m); zl += av; }
      int sv = psrc[i];
      const float* fr = ft + (long)sv*HD;
      #pragma unroll
      for(int q=0;q<4;q++){
        float a = __shfl(av, h0 + 2*q, 64);
        acc[q] = fmaf(a, fr[lane + 64*q], acc[q]);
      }
    }
    #pragma unroll
    for(int q=0;q<4;q++){
      float z = __shfl(zl, h0 + 2*q, 64);
      float zs = (z==0.f) ? 1.f : z;
      int c = lane + 64*q;
      float xv = lrelu(acc[q]/zs + LD<F32>(xin,(long)n*HD + c));
      ST<F32>(xout,(long)n*HD + c, xv);
      s4[q] += xv; q4[q] += (double)xv*(double)xv;
    }
  }
  double* ls = sm; double* lq = sm + 256;
  for(int w=0;w<4;w++){
    if(wid==w){
      #pragma unroll
      for(int q=0;q<4;q++){
        int c = lane + 64*q;
        if(w==0){ ls[c]=s4[q]; lq[c]=q4[q]; }
        else    { ls[c]+=s4[q]; lq[c]+=q4[q]; }
      }
    }
    __syncthreads();
  }
  int t = threadIdx.x;
  unsafeAtomicAdd(&dstats[t],    ls[t]);
  unsafeAtomicAdd(&dstats[HD+t], lq[t]);
}
__global__ __launch_bounds__(256) void k_agg(const int* rs, const unsigned short* psrc,
                                             const float* a_edge, const unsigned* amax,
                                             const float* ft, const void* xin, void* xout,
                                             double* dstats, const int* flag){
  extern __shared__ double smemd[];
  if(*flag) agg_body<true >(rs,psrc,a_edge,amax,ft,xin,xout,dstats,smemd);
  else      agg_body<false>(rs,psrc,a_edge,amax,ft,xin,xout,dstats,smemd);
}

// ---------------- BN params from double sums ----------------
template<bool F32> __device__ void bn_params_body(const double* dstats, const void* g,
                                                  const void* b, float* scsh, int C, double invM){
  int t = threadIdx.x;
  if(t>=C) return;
  double mu  = dstats[t]*invM;
  double var = dstats[C+t]*invM - mu*mu;
  if(var < 0.0) var = 0.0;
  float sc = LD<F32>(g,t) * rsqrtf((float)var + BN_EPS);
  scsh[t]   = sc;
  scsh[C+t] = LD<F32>(b,t) - (float)mu*sc;
}
__global__ void k_bn_params(const double* dstats, const void* g, const void* b,
                            float* scsh, int C, double invM, const int* flag){
  if(*flag) bn_params_body<true >(dstats,g,b,scsh,C,invM);
  else      bn_params_body<false>(dstats,g,b,scsh,C,invM);
}

// ---------------- K6: node BN apply, in place on d_out node section ----------------
template<bool F32> __device__ void node_apply_body(void* x, const float* scsh){
  int t = threadIdx.x;
  float sc = scsh[t], sh = scsh[HD+t];
  for(long i=(long)blockIdx.x*256+t; i<(long)N_NODES*HD; i+=(long)gridDim.x*256){
    ST<F32>(x, i, fmaf(LD<F32>(x,i), sc, sh));
  }
}
__global__ __launch_bounds__(256) void k_node_apply(void* x, const float* scsh, const int* flag){
  if(*flag) node_apply_body<true >(x,scsh);
  else      node_apply_body<false>(x,scsh);
}

// ---------------- K7: fused edge update via MFMA -> pre-BN edge into d_out edge section ----
#define LROW 132   // padded LDS row stride (f32) for the 16x128 per-wave intermediate

template<bool F32>
__device__ void edge_update_body(const void* nodeb, const void* edge_in,
                                 const int* src, const int* dst,
                                 const unsigned short* wpack,
                                 void* d_out, float* lds){
  void* edge_x = ESEC<F32>(d_out);
  const uint4* wn4 = (const uint4*)wpack;   // 4096 frags-uint4
  const uint4* we4 = wn4 + 4096;            // 512
  const uint4* wf4 = wn4 + 4608;            // 1024
  int wid   = threadIdx.x >> 6;
  int lane  = threadIdx.x & 63;
  int row16 = lane & 15;
  int kgrp  = lane >> 4;
  int e0  = blockIdx.x*64 + wid*16;
  int e_a = e0 + row16;
  int nsrc = src[e_a], ndst = dst[e_a];
  float* myl = lds + wid*(16*LROW);

  f32x4 acc_h[4], acc_l[4];
  #pragma unroll
  for(int t=0;t<4;t++){ acc_h[t]=(f32x4){0.f,0.f,0.f,0.f}; acc_l[t]=(f32x4){0.f,0.f,0.f,0.f}; }

  // ---- node GEMM: K = 512 ----
  #pragma unroll
  for(int half=0; half<2; half++){
    long rowbase = (long)(half ? ndst : nsrc) * HD;
    #pragma unroll 2
    for(int ks=0; ks<8; ks++){
      bf16x8 ah, al;
      load_split<F32>(nodeb, rowbase + ks*32 + kgrp*8, ah, al);
      const uint4* wb = wn4 + (size_t)((half*8 + ks)*4)*64 + lane;
      #pragma unroll
      for(int nt=0; nt<4; nt++){
        bf16x8 bfr = as_frag(wb[nt*64]);
        acc_h[nt] = MFMA16(ah, bfr, acc_h[nt]);
        if constexpr(F32) acc_l[nt] = MFMA16(al, bfr, acc_l[nt]);
      }
    }
  }
  #pragma unroll
  for(int nt=0; nt<4; nt++)
    #pragma unroll
    for(int j=0;j<4;j++)
      myl[(kgrp*4+j)*LROW + nt*16 + row16] = lrelu(acc_h[nt][j] + acc_l[nt][j]);

  // ---- edge-feature GEMM: K = 64 ----
  #pragma unroll
  for(int t=0;t<4;t++){ acc_h[t]=(f32x4){0.f,0.f,0.f,0.f}; acc_l[t]=(f32x4){0.f,0.f,0.f,0.f}; }
  long ebase = (long)e_a * EDGE_F;
  #pragma unroll
  for(int ks=0; ks<2; ks++){
    bf16x8 ah, al;
    load_split<F32>(edge_in, ebase + ks*32 + kgrp*8, ah, al);
    const uint4* wb = we4 + (size_t)(ks*4)*64 + lane;
    #pragma unroll
    for(int nt=0; nt<4; nt++){
      bf16x8 bfr = as_frag(wb[nt*64]);
      acc_h[nt] = MFMA16(ah, bfr, acc_h[nt]);
      if constexpr(F32) acc_l[nt] = MFMA16(al, bfr, acc_l[nt]);
    }
  }
  #pragma unroll
  for(int nt=0; nt<4; nt++)
    #pragma unroll
    for(int j=0;j<4;j++)
      myl[(kgrp*4+j)*LROW + 64 + nt*16 + row16] = lrelu(acc_h[nt][j] + acc_l[nt][j]);

  __syncthreads();

  // ---- final GEMM: K = 128 from LDS, + residual, lrelu, store ----
  #pragma unroll
  for(int t=0;t<4;t++){ acc_h[t]=(f32x4){0.f,0.f,0.f,0.f}; acc_l[t]=(f32x4){0.f,0.f,0.f,0.f}; }
  #pragma unroll
  for(int ks=0; ks<4; ks++){
    const float* ap = myl + row16*LROW + ks*32 + kgrp*8;
    float4 a0 = *(const float4*)ap;
    float4 a1 = *(const float4*)(ap+4);
    bf16x8 ah, al; split8(a0,a1,ah,al);
    const uint4* wb = wf4 + (size_t)(ks*4)*64 + lane;
    #pragma unroll
    for(int nt=0; nt<4; nt++){
      bf16x8 bfr = as_frag(wb[nt*64]);
      acc_h[nt] = MFMA16(ah, bfr, acc_h[nt]);
      acc_l[nt] = MFMA16(al, bfr, acc_l[nt]);
    }
  }
  #pragma unroll
  for(int nt=0; nt<4; nt++)
    #pragma unroll
    for(int j=0;j<4;j++){
      long e = e0 + kgrp*4 + j;
      int  c = nt*16 + row16;
      float res = LD<F32>(edge_in, e*EDGE_OUT + c);
      ST<F32>(edge_x, e*EDGE_OUT + c, lrelu(acc_h[nt][j] + acc_l[nt][j] + res));
    }
}
__global__ __launch_bounds__(256) void k_edge_update(const void* nodeb, const void* edge_in,
                                                     const int* src, const int* dst,
                                                     const unsigned short* wpack,
                                                     void* d_out, const int* flag){
  extern __shared__ float smemf[];
  if(*flag) edge_update_body<true >(nodeb,edge_in,src,dst,wpack,d_out,smemf);
  else      edge_update_body<false>(nodeb,edge_in,src,dst,wpack,d_out,smemf);
}

// ---------------- K8: edge column stats ----------------
template<bool F32> __device__ void edge_stats_body(void* d_out, double* dstats, double* sm){
  const void* ex = ESEC<F32>(d_out);
  double* ls = sm; double* lq = sm+256;
  int t = threadIdx.x;
  int c = t & 63, r0 = t >> 6;
  double s=0.0, q=0.0;
  for(long i=(long)(blockIdx.x*4 + r0)*64 + c; i < (long)N_EDGES*EDGE_OUT; i += (long)gridDim.x*4*64){
    float x = LD<F32>(ex, i);
    s += x; q += (double)x*(double)x;
  }
  ls[t]=s; lq[t]=q;
  __syncthreads();
  if(t<64){
    double ss = ls[t]+ls[t+64]+ls[t+128]+ls[t+192];
    double qq = lq[t]+lq[t+64]+lq[t+128]+lq[t+192];
    unsafeAtomicAdd(&dstats[t], ss);
    unsafeAtomicAdd(&dstats[64+t], qq);
  }
}
__global__ __launch_bounds__(256) void k_edge_stats(void* d_out, double* dstats, const int* flag){
  extern __shared__ double smemd[];
  if(*flag) edge_stats_body<true >(d_out,dstats,smemd);
  else      edge_stats_body<false>(d_out,dstats,smemd);
}

// ---------------- K9: edge BN apply, in place on d_out edge section ----------------
template<bool F32> __device__ void edge_apply_body(void* d_out, const float* scsh){
  void* ex = ESEC<F32>(d_out);
  int t = threadIdx.x;
  int c = t & 63;
  float sc = scsh[c], sh = scsh[64+c];
  for(long i=(long)blockIdx.x*256+t; i<(long)N_EDGES*EDGE_OUT; i+=(long)gridDim.x*256){
    ST<F32>(ex, i, fmaf(LD<F32>(ex,i), sc, sh));
  }
}
__global__ __launch_bounds__(256) void k_edge_apply(void* d_out, const float* scsh, const int* flag){
  if(*flag) edge_apply_body<true >(d_out,scsh);
  else      edge_apply_body<false>(d_out,scsh);
}

extern "C" void kernel_launch(void* const* d_in, const int* in_sizes, int n_in,
                              void* d_out, int out_size, void* d_ws, size_t ws_size,
                              hipStream_t stream){
  const void* node_in    = d_in[0];
  const void* edge_in    = d_in[1];
  const void* fc_w       = d_in[2];
  const void* attn_l     = d_in[3];
  const void* attn_r     = d_in[4];
  const void* ae_w1      = d_in[5];
  const void* ae_b1      = d_in[6];
  const void* ae_w2      = d_in[7];
  const void* ae_b2      = d_in[8];
  const void* bn_n_g     = d_in[9];
  const void* bn_n_b     = d_in[10];
  const void* eu_node_w  = d_in[11];
  const void* eu_edge_w  = d_in[12];
  const void* eu_final_w = d_in[13];
  const void* bn_e_g     = d_in[14];
  const void* bn_e_b     = d_in[15];
  const int*  src        = (const int*)d_in[16];
  const int*  dst        = (const int*)d_in[17];

  // ---- workspace, all inside d_ws (~70.28 MB total; proven envelope >= 70.41 MB) ----
  char* base = (char*)d_ws;
  double*   dstats_n = (double*)base;                 // 512 dbl
  double*   dstats_e = (double*)(base + 4096);        // 128 dbl
  float*    scsh_n   = (float*)(base + 5120);         // 512 f
  float*    scsh_e   = (float*)(base + 7168);         // 128 f
  int*      flag     = (int*)(base + 7680);
  char*     big      = base + 8192;
  float*    ftb      = (float*)big;                   // N*HD f32 = 51.2MB (always f32)
  float*    a_edge   = (float*)(big + 51200000);      // E*8 f32 (CSR order) = 12.8MB
  float*    a1       = (float*)(big + 64000000);      // N*8 f32
  float*    a2       = (float*)(big + 65600000);      // N*8 f32
  unsigned* amax     = (unsigned*)(big + 67200000);   // N*8 u32 -> ends 68.8MB
  unsigned short* wpack_eu = (unsigned short*)(big + 68800000);  // 90KB
  unsigned short* wpack_fc = (unsigned short*)(big + 68900000);  // 128KB
  int*      rsb      = (int*)(big + 69040000);        // NBINS ints (202KB)
  int*      cursor   = (int*)(big + 69250000);        // NBINS ints (doubles as histogram)
  int*      btot     = (int*)(big + 69460000);        // NBLK ints
  int*      bsum     = (int*)(big + 69461024);        // NBLK ints
  unsigned short* psrc = (unsigned short*)(big + 69470000); // E u16 (0.8MB) -> ends 70.27MB

  hipMemsetAsync(dstats_n, 0, 640*sizeof(double), stream);
  hipMemsetAsync(amax, 0, (size_t)N_NODES*NHEADS*sizeof(unsigned), stream);
  hipMemsetAsync(cursor, 0, NBINS*sizeof(int), stream);

  k_detect<<<1, 256, 0, stream>>>((const unsigned short*)node_in, flag);
  // CSR build (flag-independent)
  k_hist <<<(N_EDGES+255)/256, 256, 0, stream>>>(dst, cursor);
  k_scan1<<<NBLK, 256, 0, stream>>>(cursor, rsb, btot);
  k_scan2<<<1, 256, 0, stream>>>(btot, bsum);
  k_scan3<<<NBLK, 256, 0, stream>>>(rsb, bsum, cursor);
  // node projection (MFMA) + attention scalars
  k_pack_fc<<<256, 256, 0, stream>>>(fc_w, wpack_fc, flag);
  k_node_proj<<<(N_NODES+63)/64, 256, 0, stream>>>(node_in, wpack_fc, ftb, flag);
  k_attn<<<N_NODES*NHEADS/8, 256, 0, stream>>>(ftb, attn_l, attn_r, a1, a2, flag);
  // edge attention -> CSR slots + segment max
  k_edge_attn<<<N_EDGES/8, 256, 12448, stream>>>(edge_in, ae_w1, ae_b1, ae_w2, ae_b2,
                                                 a1, a2, src, dst, cursor, psrc,
                                                 a_edge, amax, flag);
  // fused softmax + aggregation + residual + lrelu + BN stats (no atomic scatter)
  k_agg<<<960, 256, 4096, stream>>>(rsb, psrc, a_edge, amax, ftb, node_in, d_out,
                                    dstats_n, flag);
  k_bn_params<<<1, 256, 0, stream>>>(dstats_n, bn_n_g, bn_n_b, scsh_n, HD, 1.0/N_NODES, flag);
  k_node_apply<<<2048, 256, 0, stream>>>(d_out, scsh_n, flag);
  // edge update (MFMA) + BN
  k_pack_w<<<176, 256, 0, stream>>>(eu_node_w, eu_edge_w, eu_final_w, wpack_eu, flag);
  k_edge_update<<<N_EDGES/64, 256, 4*16*LROW*4, stream>>>(d_out, edge_in, src, dst,
                                                          wpack_eu, d_out, flag);
  k_edge_stats<<<512, 256, 4096, stream>>>(d_out, dstats_e, flag);
  k_bn_params<<<1, 256, 0, stream>>>(dstats_e, bn_e_g, bn_e_b, scsh_e, EDGE_OUT, 1.0/N_EDGES, flag);
  k_edge_apply<<<2048, 256, 0, stream>>>(d_out, scsh_e, flag);
  (void)ws_size; (void)out_size; (void)n_in; (void)in_sizes;
}

// Round 4
// 925.842 us; speedup vs baseline: 3.4545x; 1.1793x over previous
//
#include <hip/hip_runtime.h>
#include <hip/hip_bf16.h>

typedef __hip_bfloat16 bf16;

#define N_NODES 50000
#define N_EDGES 400000
#define IN_DIM  256
#define EDGE_F  64
#define OUT_DIM 32
#define EDGE_OUT 64
#define NHEADS  8
#define HD      256   // NHEADS*OUT_DIM
#define ALPHA   0.2f
#define BN_EPS  1e-5f

#define NBINS 50432   // 197*256, >= N_NODES+1
#define NBLK  197

__device__ __forceinline__ float b2f(bf16 v){ return __bfloat162float(v); }
__device__ __forceinline__ bf16  f2b(float v){ return __float2bfloat16(v); }
__device__ __forceinline__ float lrelu(float x){ return x > 0.f ? x : ALPHA*x; }
__device__ __forceinline__ unsigned fenc(float f){ unsigned u=__float_as_uint(f); return (u&0x80000000u)? ~u : (u|0x80000000u); }
__device__ __forceinline__ float fdec(unsigned k){ return (k&0x80000000u)? __uint_as_float(k&0x7fffffffu) : __uint_as_float(~k); }

// dtype-adaptive load/store: F32=true -> fp32 buffer, else bf16 buffer
template<bool F32> __device__ __forceinline__ float LD(const void* p, long i){
  if constexpr (F32) return ((const float*)p)[i];
  else               return b2f(((const bf16*)p)[i]);
}
template<bool F32> __device__ __forceinline__ void ST(void* p, long i, float v){
  if constexpr (F32) ((float*)p)[i] = v;
  else               ((bf16*)p)[i] = f2b(v);
}
// edge-section base inside d_out: skip N*HD elements of the flag-selected dtype
template<bool F32> __device__ __forceinline__ void* ESEC(void* out){
  return (char*)out + (size_t)N_NODES*HD*(F32?4:2);
}

// ---------------- MFMA fragment helpers (16x16x32 bf16) ----------------
typedef __attribute__((ext_vector_type(8))) short bf16x8;
typedef __attribute__((ext_vector_type(4))) float f32x4;

union PackU { uint4 u; bf16x8 v; };
__device__ __forceinline__ bf16x8 as_frag(uint4 w){ PackU p; p.u = w; return p.v; }
__device__ __forceinline__ bf16x8 zero_frag(){ PackU p; p.u = make_uint4(0,0,0,0); return p.v; }

#define MFMA16(a,b,c) __builtin_amdgcn_mfma_f32_16x16x32_bf16(a,b,c,0,0,0)

// split 8 f32 into hi (truncated-top-16) and lo (bf16 of exact remainder)
__device__ __forceinline__ void split8(float4 a, float4 b, bf16x8& hi, bf16x8& lo){
  float v[8] = {a.x,a.y,a.z,a.w,b.x,b.y,b.z,b.w};
  unsigned hu[4], lu[4];
  #pragma unroll
  for(int i=0;i<4;i++){
    unsigned u0 = __float_as_uint(v[2*i]);
    unsigned u1 = __float_as_uint(v[2*i+1]);
    unsigned h0 = u0 & 0xffff0000u, h1 = u1 & 0xffff0000u;
    hu[i] = (u0>>16) | h1;
    float l0 = v[2*i]   - __uint_as_float(h0);
    float l1 = v[2*i+1] - __uint_as_float(h1);
    union { bf16 h; unsigned short s; } c0, c1; c0.h = f2b(l0); c1.h = f2b(l1);
    lu[i] = (unsigned)c0.s | ((unsigned)c1.s << 16);
  }
  PackU H,L;
  H.u = make_uint4(hu[0],hu[1],hu[2],hu[3]);
  L.u = make_uint4(lu[0],lu[1],lu[2],lu[3]);
  hi = H.v; lo = L.v;
}

// load 8 consecutive elements -> hi/lo A-fragment regs
template<bool F32> __device__ __forceinline__ void load_split(const void* p, long off, bf16x8& hi, bf16x8& lo){
  if constexpr(F32){
    const float* f = (const float*)p + off;
    float4 a = *(const float4*)f;
    float4 b = *(const float4*)(f+4);
    split8(a,b,hi,lo);
  } else {
    hi = as_frag(*(const uint4*)((const bf16*)p + off));
    lo = zero_frag();
  }
}

// ---- K0: input-dtype detector ----
__global__ __launch_bounds__(256) void k_detect(const unsigned short* __restrict__ u,
                                                int* __restrict__ flag){
  __shared__ int cnt;
  if(threadIdx.x==0) cnt=0;
  __syncthreads();
  int local=0;
  for(int i=threadIdx.x;i<8192;i+=256){
    int e = (u[i]>>7)&0xFF;
    if(e>=200) local++;
  }
  atomicAdd(&cnt, local);
  __syncthreads();
  if(threadIdx.x==0) *flag = (cnt>64) ? 1 : 0;   // 1 => buffers are fp32
}

// ---------------- CSR build: histogram + 2-level scan (dst only) ----------------
__global__ __launch_bounds__(256) void k_hist(const int* __restrict__ dst, int* __restrict__ cnt){
  int e = blockIdx.x*256 + threadIdx.x;
  if(e < N_EDGES){
    unsigned d = (unsigned)dst[e];
    if(d < N_NODES) atomicAdd(&cnt[d], 1);
  }
}
__global__ __launch_bounds__(256) void k_scan1(const int* __restrict__ cnt, int* __restrict__ rs,
                                               int* __restrict__ btot){
  __shared__ int s[256];
  int t = threadIdx.x; int i = blockIdx.x*256 + t;
  int v = cnt[i]; s[t] = v; __syncthreads();
  for(int off=1; off<256; off<<=1){
    int x = (t>=off) ? s[t-off] : 0; __syncthreads();
    s[t] += x; __syncthreads();
  }
  rs[i] = s[t] - v;
  if(t==255) btot[blockIdx.x] = s[t];
}
__global__ __launch_bounds__(256) void k_scan2(const int* __restrict__ btot, int* __restrict__ bsum){
  __shared__ int s[256];
  int t = threadIdx.x;
  int v = (t<NBLK) ? btot[t] : 0; s[t] = v; __syncthreads();
  for(int off=1; off<256; off<<=1){
    int x = (t>=off) ? s[t-off] : 0; __syncthreads();
    s[t] += x; __syncthreads();
  }
  if(t<NBLK) bsum[t] = s[t] - v;
}
__global__ __launch_bounds__(256) void k_scan3(int* __restrict__ rs, const int* __restrict__ bsum,
                                               int* __restrict__ cursor){
  int i = blockIdx.x*256 + threadIdx.x;
  int r = rs[i] + bsum[blockIdx.x];
  rs[i] = r; cursor[i] = r;
}

// ---------------- K6b: generic weight pack into MFMA B-fragment order (bf16) ----------
// element ((ks*NT+nt)*64+lane)*8+j  <-  W[ks*32 + (lane>>4)*8 + j][nt*16 + (lane&15)]
template<bool F32> __device__ void pack_body(const void* wn, const void* we, const void* wf,
                                             unsigned short* out){
  int i = blockIdx.x*256 + threadIdx.x;
  if(i >= 45056) return;
  const void* srcp; int idx;
  if(i < 32768){ srcp = wn; idx = i; }
  else if(i < 36864){ srcp = we; idx = i - 32768; }
  else { srcp = wf; idx = i - 36864; }
  int j = idx & 7, lane = (idx>>3)&63, nt = (idx>>9)&3, ks = idx>>11;
  int k = ks*32 + ((lane>>4)<<3) + j;
  int n = (nt<<4) + (lane&15);
  union { bf16 h; unsigned short s; } u;
  u.h = f2b(LD<F32>(srcp, (long)k*EDGE_OUT + n));
  out[i] = u.s;
}
__global__ __launch_bounds__(256) void k_pack_w(const void* wn, const void* we, const void* wf,
                                                unsigned short* out, const int* flag){
  if(*flag) pack_body<true >(wn,we,wf,out);
  else      pack_body<false>(wn,we,wf,out);
}
// fc_w pack: K=256, Nout=256 (NT=16), 65536 elems
template<bool F32> __device__ void pack_fc_body(const void* w, unsigned short* out){
  int i = blockIdx.x*256 + threadIdx.x;
  int j = i&7, lane = (i>>3)&63, nt = (i>>9)&15, ks = i>>13;
  int k = ks*32 + ((lane>>4)<<3) + j;
  int n = (nt<<4) + (lane&15);
  union { bf16 h; unsigned short s; } u;
  u.h = f2b(LD<F32>(w, (long)k*HD + n));
  out[i] = u.s;
}
__global__ __launch_bounds__(256) void k_pack_fc(const void* w, unsigned short* out, const int* flag){
  if(*flag) pack_fc_body<true >(w,out);
  else      pack_fc_body<false>(w,out);
}

// ---------------- K1: ft = node_inputs @ fc_w via MFMA -> ftb (f32 workspace) -------
// 4 waves/block, each wave: 16 rows x 256 cols.
template<bool F32> __device__ void nproj_body(const void* x, const unsigned short* wpf, float* ft){
  const uint4* w4 = (const uint4*)wpf;
  int wid = threadIdx.x>>6, lane = threadIdx.x&63;
  int row16 = lane&15, kgrp = lane>>4;
  int r0 = blockIdx.x*64 + wid*16;
  long arow = r0 + row16; if(arow >= N_NODES) arow = N_NODES-1;
  f32x4 acc[16];
  #pragma unroll
  for(int nt=0;nt<16;nt++) acc[nt] = (f32x4){0.f,0.f,0.f,0.f};
  #pragma unroll 2
  for(int ks=0;ks<8;ks++){
    bf16x8 ah, al;
    load_split<F32>(x, arow*IN_DIM + ks*32 + kgrp*8, ah, al);
    const uint4* wb = w4 + (size_t)(ks*16)*64 + lane;
    #pragma unroll
    for(int nt=0;nt<16;nt++){
      bf16x8 b = as_frag(wb[nt*64]);
      if constexpr(F32) acc[nt] = MFMA16(al, b, acc[nt]);
      acc[nt] = MFMA16(ah, b, acc[nt]);
    }
  }
  #pragma unroll
  for(int nt=0;nt<16;nt++)
    #pragma unroll
    for(int j=0;j<4;j++){
      int r = r0 + kgrp*4 + j;
      if(r < N_NODES) ft[(long)r*HD + nt*16 + row16] = acc[nt][j];
    }
}
__global__ __launch_bounds__(256) void k_node_proj(const void* x, const unsigned short* wpf,
                                                   float* ft, const int* flag){
  if(*flag) nproj_body<true >(x,wpf,ft);
  else      nproj_body<false>(x,wpf,ft);
}

// ---------------- K2: a1/a2 per-(node,head) dots (ft is f32) ----------------
template<bool F32> __device__ void attn_body(const float* ft, const void* al, const void* ar,
                                             float* a1, float* a2){
  int gid = blockIdx.x*8 + (threadIdx.x>>5);
  int d   = threadIdx.x & 31;
  int h   = gid & 7;
  float v  = ft[(long)gid*OUT_DIM + d];
  float s1 = v * LD<F32>(al, h*OUT_DIM + d);
  float s2 = v * LD<F32>(ar, h*OUT_DIM + d);
  for(int o=16;o>0;o>>=1){ s1 += __shfl_down(s1,o,32); s2 += __shfl_down(s2,o,32); }
  if(d==0){ a1[gid]=s1; a2[gid]=s2; }
}
__global__ __launch_bounds__(256) void k_attn(const float* ft, const void* al, const void* ar,
                                              float* a1, float* a2, const int* flag){
  if(*flag) attn_body<true >(ft,al,ar,a1,a2);
  else      attn_body<false>(ft,al,ar,a1,a2);
}

// ---------------- K3: edge-attn MLP + lrelu + segment-max + CSR slot write ----------
template<bool F32> __device__ void edge_attn_body(const void* ein, const void* w1, const void* b1,
                                                  const void* w2, const void* b2,
                                                  const float* a1, const float* a2,
                                                  const int* src, const int* dst,
                                                  int* cursor, unsigned short* psrc,
                                                  float* a_edge, unsigned* amax, float* sm){
  float* sw1 = sm;            // 2048
  float* sw2 = sw1 + 2048;    // 256
  float* sb1 = sw2 + 256;     // 32
  float* sb2 = sb1 + 32;      // 8
  float* se  = sb2 + 8;       // 8*64
  float* st  = se  + 512;     // 8*32
  int t = threadIdx.x;
  #pragma unroll
  for(int i=0;i<8;i++) sw1[i*256+t] = LD<F32>(w1, i*256+t);
  sw2[t] = LD<F32>(w2, t);
  if(t<OUT_DIM) sb1[t]=LD<F32>(b1,t);
  if(t<NHEADS)  sb2[t]=LD<F32>(b2,t);
  int e0 = blockIdx.x*8;
  #pragma unroll
  for(int i=0;i<2;i++){ int idx=i*256+t; se[idx] = LD<F32>(ein,(long)e0*EDGE_F + idx); }
  __syncthreads();
  int r = t>>5, j = t&31;
  float acc = sb1[j];
  #pragma unroll 4
  for(int k=0;k<EDGE_F;k++) acc += se[r*64+k]*sw1[k*OUT_DIM+j];
  st[r*32+j] = lrelu(acc);
  __syncthreads();
  if(t<64){
    int rr = t>>3, h = t&7;
    float s = sb2[h];
    #pragma unroll
    for(int jj=0;jj<OUT_DIM;jj++) s += st[rr*32+jj]*sw2[jj*NHEADS+h];
    int e = e0+rr;
    int sv = src[e], dv = dst[e];
    float av = lrelu(a1[sv*NHEADS+h] + a2[dv*NHEADS+h] + s);   // TEMP==1
    int pos = 0;
    if(h==0) pos = atomicAdd(&cursor[dv], 1);
    pos = __shfl(pos, rr*8, 64);
    a_edge[(long)pos*NHEADS + h] = av;
    if(h==0) psrc[pos] = (unsigned short)sv;
    atomicMax(&amax[dv*NHEADS+h], fenc(av));
  }
}
__global__ __launch_bounds__(256) void k_edge_attn(const void* ein, const void* w1, const void* b1,
                                                   const void* w2, const void* b2,
                                                   const float* a1, const float* a2,
                                                   const int* src, const int* dst,
                                                   int* cursor, unsigned short* psrc,
                                                   float* a_edge, unsigned* amax, const int* flag){
  extern __shared__ float smemf[];
  if(*flag) edge_attn_body<true >(ein,w1,b1,w2,b2,a1,a2,src,dst,cursor,psrc,a_edge,amax,smemf);
  else      edge_attn_body<false>(ein,w1,b1,w2,b2,a1,a2,src,dst,cursor,psrc,a_edge,amax,smemf);
}

// ---------------- K4: fused CSR aggregation + softmax + residual + lrelu + BN stats --
template<bool F32> __device__ void agg_body(const int* rs, const unsigned short* psrc,
                                            const float* a_edge, const unsigned* amax,
                                            const float* ft, const void* xin, void* xout,
                                            double* dstats, double* sm){
  int wid = threadIdx.x>>6, lane = threadIdx.x&63;
  int gw = blockIdx.x*4 + wid, nw = gridDim.x*4;
  int h0 = lane>>5;
  double s4[4]={0,0,0,0}, q4[4]={0,0,0,0};
  for(int n=gw; n<N_NODES; n+=nw){
    int b0 = rs[n], b1 = rs[n+1];
    if(b1 > N_EDGES) b1 = N_EDGES;
    if(b0 > b1) b0 = b1;
    float m = (lane<8) ? fdec(amax[n*NHEADS+lane]) : 0.f;
    float zl = 0.f;
    float acc[4] = {0,0,0,0};
    for(int i=b0;i<b1;++i){
      float av = 0.f;
      if(lane<8){ av = __expf(a_edge[(long)i*NHEADS+lane] - m); zl += av; }
      int sv = psrc[i];
      const float* fr = ft + (long)sv*HD;
      #pragma unroll
      for(int q=0;q<4;q++){
        float a = __shfl(av, h0 + 2*q, 64);
        acc[q] = fmaf(a, fr[lane + 64*q], acc[q]);
      }
    }
    #pragma unroll
    for(int q=0;q<4;q++){
      float z = __shfl(zl, h0 + 2*q, 64);
      float zs = (z==0.f) ? 1.f : z;
      int c = lane + 64*q;
      float xv = lrelu(acc[q]/zs + LD<F32>(xin,(long)n*HD + c));
      ST<F32>(xout,(long)n*HD + c, xv);
      s4[q] += xv; q4[q] += (double)xv*(double)xv;
    }
  }
  double* ls = sm; double* lq = sm + 256;
  for(int w=0;w<4;w++){
    if(wid==w){
      #pragma unroll
      for(int q=0;q<4;q++){
        int c = lane + 64*q;
        if(w==0){ ls[c]=s4[q]; lq[c]=q4[q]; }
        else    { ls[c]+=s4[q]; lq[c]+=q4[q]; }
      }
    }
    __syncthreads();
  }
  int t = threadIdx.x;
  unsafeAtomicAdd(&dstats[t],    ls[t]);
  unsafeAtomicAdd(&dstats[HD+t], lq[t]);
}
__global__ __launch_bounds__(256) void k_agg(const int* rs, const unsigned short* psrc,
                                             const float* a_edge, const unsigned* amax,
                                             const float* ft, const void* xin, void* xout,
                                             double* dstats, const int* flag){
  extern __shared__ double smemd[];
  if(*flag) agg_body<true >(rs,psrc,a_edge,amax,ft,xin,xout,dstats,smemd);
  else      agg_body<false>(rs,psrc,a_edge,amax,ft,xin,xout,dstats,smemd);
}

// ---------------- BN params from double sums ----------------
template<bool F32> __device__ void bn_params_body(const double* dstats, const void* g,
                                                  const void* b, float* scsh, int C, double invM){
  int t = threadIdx.x;
  if(t>=C) return;
  double mu  = dstats[t]*invM;
  double var = dstats[C+t]*invM - mu*mu;
  if(var < 0.0) var = 0.0;
  float sc = LD<F32>(g,t) * rsqrtf((float)var + BN_EPS);
  scsh[t]   = sc;
  scsh[C+t] = LD<F32>(b,t) - (float)mu*sc;
}
__global__ void k_bn_params(const double* dstats, const void* g, const void* b,
                            float* scsh, int C, double invM, const int* flag){
  if(*flag) bn_params_body<true >(dstats,g,b,scsh,C,invM);
  else      bn_params_body<false>(dstats,g,b,scsh,C,invM);
}

// ---------------- K6: node BN apply, in place on d_out node section ----------------
template<bool F32> __device__ void node_apply_body(void* x, const float* scsh){
  int t = threadIdx.x;
  float sc = scsh[t], sh = scsh[HD+t];
  for(long i=(long)blockIdx.x*256+t; i<(long)N_NODES*HD; i+=(long)gridDim.x*256){
    ST<F32>(x, i, fmaf(LD<F32>(x,i), sc, sh));
  }
}
__global__ __launch_bounds__(256) void k_node_apply(void* x, const float* scsh, const int* flag){
  if(*flag) node_apply_body<true >(x,scsh);
  else      node_apply_body<false>(x,scsh);
}

// ---------------- K6c: P/Q = node_out @ Wn_top / Wn_bot  (MFMA, per NODE) ----------
// P[n][c] = sum_k nodeout[n][k] * Wn[k][c],  Q[n][c] = sum_k nodeout[n][k] * Wn[256+k][c]
// reuses wpack_eu's wn section: ks 0..7 = top half, ks 8..15 = bottom half.
template<bool F32> __device__ void pq_body(const void* nodeb, const unsigned short* wpack,
                                           float* P, float* Q){
  const uint4* wn4 = (const uint4*)wpack;
  int wid = threadIdx.x>>6, lane = threadIdx.x&63;
  int row16 = lane&15, kgrp = lane>>4;
  int r0 = blockIdx.x*64 + wid*16;
  long arow = r0 + row16; if(arow >= N_NODES) arow = N_NODES-1;
  f32x4 pacc[4], qacc[4];
  #pragma unroll
  for(int nt=0;nt<4;nt++){ pacc[nt]=(f32x4){0.f,0.f,0.f,0.f}; qacc[nt]=(f32x4){0.f,0.f,0.f,0.f}; }
  #pragma unroll 2
  for(int ks=0;ks<8;ks++){
    bf16x8 ah, al;
    load_split<F32>(nodeb, arow*HD + ks*32 + kgrp*8, ah, al);
    const uint4* wbP = wn4 + (size_t)(ks*4)*64 + lane;
    const uint4* wbQ = wn4 + (size_t)((8+ks)*4)*64 + lane;
    #pragma unroll
    for(int nt=0;nt<4;nt++){
      bf16x8 bP = as_frag(wbP[nt*64]);
      bf16x8 bQ = as_frag(wbQ[nt*64]);
      pacc[nt] = MFMA16(ah, bP, pacc[nt]);
      qacc[nt] = MFMA16(ah, bQ, qacc[nt]);
      if constexpr(F32){
        pacc[nt] = MFMA16(al, bP, pacc[nt]);
        qacc[nt] = MFMA16(al, bQ, qacc[nt]);
      }
    }
  }
  #pragma unroll
  for(int nt=0;nt<4;nt++)
    #pragma unroll
    for(int j=0;j<4;j++){
      int r = r0 + kgrp*4 + j;
      if(r < N_NODES){
        P[(long)r*64 + nt*16 + row16] = pacc[nt][j];
        Q[(long)r*64 + nt*16 + row16] = qacc[nt][j];
      }
    }
}
__global__ __launch_bounds__(256) void k_pq(const void* nodeb, const unsigned short* wpack,
                                            float* P, float* Q, const int* flag){
  if(*flag) pq_body<true >(nodeb,wpack,P,Q);
  else      pq_body<false>(nodeb,wpack,P,Q);
}

// ---------------- K7: fused edge update via MFMA (P/Q-factored) ----------------
// per edge: nf = lrelu(P[src]+Q[dst]) (no GEMM), ef = lrelu(e_in @ We) (K=64),
//           out = lrelu([nf|ef] @ Wf + e_in) (K=128).
#define EF_LROW 68   // padded LDS row stride (f32) for the 16x64 per-wave ef tile

template<bool F32>
__device__ void edge_update_body(const float* P, const float* Q, const void* edge_in,
                                 const int* src, const int* dst,
                                 const unsigned short* wpack,
                                 void* d_out, float* lds){
  void* edge_x = ESEC<F32>(d_out);
  const uint4* we4 = ((const uint4*)wpack) + 4096;
  const uint4* wf4 = ((const uint4*)wpack) + 4608;
  int wid   = threadIdx.x >> 6;
  int lane  = threadIdx.x & 63;
  int row16 = lane & 15;
  int kgrp  = lane >> 4;
  int e0  = blockIdx.x*64 + wid*16;
  int e_a = e0 + row16;
  int nsrc = src[e_a], ndst = dst[e_a];
  float* myl = lds + wid*(16*EF_LROW);

  f32x4 acc_h[4], acc_l[4];
  #pragma unroll
  for(int t=0;t<4;t++){ acc_h[t]=(f32x4){0.f,0.f,0.f,0.f}; acc_l[t]=(f32x4){0.f,0.f,0.f,0.f}; }

  // ---- ef GEMM: K = 64 ----
  long ebase = (long)e_a * EDGE_F;
  #pragma unroll
  for(int ks=0; ks<2; ks++){
    bf16x8 ah, al;
    load_split<F32>(edge_in, ebase + ks*32 + kgrp*8, ah, al);
    const uint4* wb = we4 + (size_t)(ks*4)*64 + lane;
    #pragma unroll
    for(int nt=0; nt<4; nt++){
      bf16x8 bfr = as_frag(wb[nt*64]);
      acc_h[nt] = MFMA16(ah, bfr, acc_h[nt]);
      if constexpr(F32) acc_l[nt] = MFMA16(al, bfr, acc_l[nt]);
    }
  }
  #pragma unroll
  for(int nt=0; nt<4; nt++)
    #pragma unroll
    for(int j=0;j<4;j++)
      myl[(kgrp*4+j)*EF_LROW + nt*16 + row16] = lrelu(acc_h[nt][j] + acc_l[nt][j]);

  __syncthreads();   // ef C-layout -> A-layout redistribution

  // ---- final GEMM: K = 128 (k 0..63 = nf from P/Q gather, k 64..127 = ef from LDS) ----
  #pragma unroll
  for(int t=0;t<4;t++){ acc_h[t]=(f32x4){0.f,0.f,0.f,0.f}; acc_l[t]=(f32x4){0.f,0.f,0.f,0.f}; }
  #pragma unroll
  for(int ks=0; ks<2; ks++){
    const float* pp = P + (long)nsrc*64 + ks*32 + kgrp*8;
    const float* qq = Q + (long)ndst*64 + ks*32 + kgrp*8;
    float4 p0 = *(const float4*)pp, p1 = *(const float4*)(pp+4);
    float4 q0 = *(const float4*)qq, q1 = *(const float4*)(qq+4);
    float4 v0, v1;
    v0.x = lrelu(p0.x+q0.x); v0.y = lrelu(p0.y+q0.y);
    v0.z = lrelu(p0.z+q0.z); v0.w = lrelu(p0.w+q0.w);
    v1.x = lrelu(p1.x+q1.x); v1.y = lrelu(p1.y+q1.y);
    v1.z = lrelu(p1.z+q1.z); v1.w = lrelu(p1.w+q1.w);
    bf16x8 ah, al; split8(v0, v1, ah, al);
    const uint4* wb = wf4 + (size_t)(ks*4)*64 + lane;
    #pragma unroll
    for(int nt=0; nt<4; nt++){
      bf16x8 bfr = as_frag(wb[nt*64]);
      acc_h[nt] = MFMA16(ah, bfr, acc_h[nt]);
      acc_l[nt] = MFMA16(al, bfr, acc_l[nt]);
    }
  }
  #pragma unroll
  for(int ks=2; ks<4; ks++){
    const float* ap = myl + row16*EF_LROW + (ks-2)*32 + kgrp*8;
    float4 a0 = *(const float4*)ap;
    float4 a1 = *(const float4*)(ap+4);
    bf16x8 ah, al; split8(a0, a1, ah, al);
    const uint4* wb = wf4 + (size_t)(ks*4)*64 + lane;
    #pragma unroll
    for(int nt=0; nt<4; nt++){
      bf16x8 bfr = as_frag(wb[nt*64]);
      acc_h[nt] = MFMA16(ah, bfr, acc_h[nt]);
      acc_l[nt] = MFMA16(al, bfr, acc_l[nt]);
    }
  }
  #pragma unroll
  for(int nt=0; nt<4; nt++)
    #pragma unroll
    for(int j=0;j<4;j++){
      long e = e0 + kgrp*4 + j;
      int  c = nt*16 + row16;
      float res = LD<F32>(edge_in, e*EDGE_OUT + c);
      ST<F32>(edge_x, e*EDGE_OUT + c, lrelu(acc_h[nt][j] + acc_l[nt][j] + res));
    }
}
__global__ __launch_bounds__(256) void k_edge_update(const float* P, const float* Q,
                                                     const void* edge_in,
                                                     const int* src, const int* dst,
                                                     const unsigned short* wpack,
                                                     void* d_out, const int* flag){
  extern __shared__ float smemf[];
  if(*flag) edge_update_body<true >(P,Q,edge_in,src,dst,wpack,d_out,smemf);
  else      edge_update_body<false>(P,Q,edge_in,src,dst,wpack,d_out,smemf);
}

// ---------------- K8: edge column stats ----------------
template<bool F32> __device__ void edge_stats_body(void* d_out, double* dstats, double* sm){
  const void* ex = ESEC<F32>(d_out);
  double* ls = sm; double* lq = sm+256;
  int t = threadIdx.x;
  int c = t & 63, r0 = t >> 6;
  double s=0.0, q=0.0;
  for(long i=(long)(blockIdx.x*4 + r0)*64 + c; i < (long)N_EDGES*EDGE_OUT; i += (long)gridDim.x*4*64){
    float x = LD<F32>(ex, i);
    s += x; q += (double)x*(double)x;
  }
  ls[t]=s; lq[t]=q;
  __syncthreads();
  if(t<64){
    double ss = ls[t]+ls[t+64]+ls[t+128]+ls[t+192];
    double qq = lq[t]+lq[t+64]+lq[t+128]+lq[t+192];
    unsafeAtomicAdd(&dstats[t], ss);
    unsafeAtomicAdd(&dstats[64+t], qq);
  }
}
__global__ __launch_bounds__(256) void k_edge_stats(void* d_out, double* dstats, const int* flag){
  extern __shared__ double smemd[];
  if(*flag) edge_stats_body<true >(d_out,dstats,smemd);
  else      edge_stats_body<false>(d_out,dstats,smemd);
}

// ---------------- K9: edge BN apply, in place on d_out edge section ----------------
template<bool F32> __device__ void edge_apply_body(void* d_out, const float* scsh){
  void* ex = ESEC<F32>(d_out);
  int t = threadIdx.x;
  int c = t & 63;
  float sc = scsh[c], sh = scsh[64+c];
  for(long i=(long)blockIdx.x*256+t; i<(long)N_EDGES*EDGE_OUT; i+=(long)gridDim.x*256){
    ST<F32>(ex, i, fmaf(LD<F32>(ex,i), sc, sh));
  }
}
__global__ __launch_bounds__(256) void k_edge_apply(void* d_out, const float* scsh, const int* flag){
  if(*flag) edge_apply_body<true >(d_out,scsh);
  else      edge_apply_body<false>(d_out,scsh);
}

extern "C" void kernel_launch(void* const* d_in, const int* in_sizes, int n_in,
                              void* d_out, int out_size, void* d_ws, size_t ws_size,
                              hipStream_t stream){
  const void* node_in    = d_in[0];
  const void* edge_in    = d_in[1];
  const void* fc_w       = d_in[2];
  const void* attn_l     = d_in[3];
  const void* attn_r     = d_in[4];
  const void* ae_w1      = d_in[5];
  const void* ae_b1      = d_in[6];
  const void* ae_w2      = d_in[7];
  const void* ae_b2      = d_in[8];
  const void* bn_n_g     = d_in[9];
  const void* bn_n_b     = d_in[10];
  const void* eu_node_w  = d_in[11];
  const void* eu_edge_w  = d_in[12];
  const void* eu_final_w = d_in[13];
  const void* bn_e_g     = d_in[14];
  const void* bn_e_b     = d_in[15];
  const int*  src        = (const int*)d_in[16];
  const int*  dst        = (const int*)d_in[17];

  // ---- workspace, all inside d_ws (~70.28 MB total; proven envelope >= 70.41 MB) ----
  char* base = (char*)d_ws;
  double*   dstats_n = (double*)base;                 // 512 dbl
  double*   dstats_e = (double*)(base + 4096);        // 128 dbl
  float*    scsh_n   = (float*)(base + 5120);         // 512 f
  float*    scsh_e   = (float*)(base + 7168);         // 128 f
  int*      flag     = (int*)(base + 7680);
  char*     big      = base + 8192;
  float*    ftb      = (float*)big;                   // N*HD f32 = 51.2MB (always f32)
  float*    Pb       = (float*)big;                   // N*64 f32 = 12.8MB (reuses ftb after k_agg)
  float*    Qb       = (float*)(big + 12800000);      // N*64 f32 = 12.8MB
  float*    a_edge   = (float*)(big + 51200000);      // E*8 f32 (CSR order) = 12.8MB
  float*    a1       = (float*)(big + 64000000);      // N*8 f32
  float*    a2       = (float*)(big + 65600000);      // N*8 f32
  unsigned* amax     = (unsigned*)(big + 67200000);   // N*8 u32 -> ends 68.8MB
  unsigned short* wpack_eu = (unsigned short*)(big + 68800000);  // 90KB
  unsigned short* wpack_fc = (unsigned short*)(big + 68900000);  // 128KB
  int*      rsb      = (int*)(big + 69040000);        // NBINS ints (202KB)
  int*      cursor   = (int*)(big + 69250000);        // NBINS ints (doubles as histogram)
  int*      btot     = (int*)(big + 69460000);        // NBLK ints
  int*      bsum     = (int*)(big + 69461024);        // NBLK ints
  unsigned short* psrc = (unsigned short*)(big + 69470000); // E u16 (0.8MB) -> ends 70.27MB

  hipMemsetAsync(dstats_n, 0, 640*sizeof(double), stream);
  hipMemsetAsync(amax, 0, (size_t)N_NODES*NHEADS*sizeof(unsigned), stream);
  hipMemsetAsync(cursor, 0, NBINS*sizeof(int), stream);

  k_detect<<<1, 256, 0, stream>>>((const unsigned short*)node_in, flag);
  // CSR build (flag-independent)
  k_hist <<<(N_EDGES+255)/256, 256, 0, stream>>>(dst, cursor);
  k_scan1<<<NBLK, 256, 0, stream>>>(cursor, rsb, btot);
  k_scan2<<<1, 256, 0, stream>>>(btot, bsum);
  k_scan3<<<NBLK, 256, 0, stream>>>(rsb, bsum, cursor);
  // node projection (MFMA) + attention scalars
  k_pack_fc<<<256, 256, 0, stream>>>(fc_w, wpack_fc, flag);
  k_pack_w<<<176, 256, 0, stream>>>(eu_node_w, eu_edge_w, eu_final_w, wpack_eu, flag);
  k_node_proj<<<(N_NODES+63)/64, 256, 0, stream>>>(node_in, wpack_fc, ftb, flag);
  k_attn<<<N_NODES*NHEADS/8, 256, 0, stream>>>(ftb, attn_l, attn_r, a1, a2, flag);
  // edge attention -> CSR slots + segment max
  k_edge_attn<<<N_EDGES/8, 256, 12448, stream>>>(edge_in, ae_w1, ae_b1, ae_w2, ae_b2,
                                                 a1, a2, src, dst, cursor, psrc,
                                                 a_edge, amax, flag);
  // fused softmax + aggregation + residual + lrelu + BN stats (no atomic scatter)
  k_agg<<<960, 256, 4096, stream>>>(rsb, psrc, a_edge, amax, ftb, node_in, d_out,
                                    dstats_n, flag);
  k_bn_params<<<1, 256, 0, stream>>>(dstats_n, bn_n_g, bn_n_b, scsh_n, HD, 1.0/N_NODES, flag);
  k_node_apply<<<2048, 256, 0, stream>>>(d_out, scsh_n, flag);
  // per-node P/Q projection (ftb is dead after k_agg; reuse its space)
  k_pq<<<(N_NODES+63)/64, 256, 0, stream>>>(d_out, wpack_eu, Pb, Qb, flag);
  // edge update (MFMA, P/Q-factored) + BN
  k_edge_update<<<N_EDGES/64, 256, 4*16*EF_LROW*4, stream>>>(Pb, Qb, edge_in, src, dst,
                                                             wpack_eu, d_out, flag);
  k_edge_stats<<<512, 256, 4096, stream>>>(d_out, dstats_e, flag);
  k_bn_params<<<1, 256, 0, stream>>>(dstats_e, bn_e_g, bn_e_b, scsh_e, EDGE_OUT, 1.0/N_EDGES, flag);
  k_edge_apply<<<2048, 256, 0, stream>>>(d_out, scsh_e, flag);
  (void)ws_size; (void)out_size; (void)n_in; (void)in_sizes;
}

// Round 5
// 826.612 us; speedup vs baseline: 3.8692x; 1.1200x over previous
//
#include <hip/hip_runtime.h>
#include <hip/hip_bf16.h>

typedef __hip_bfloat16 bf16;

#define N_NODES 50000
#define N_EDGES 400000
#define IN_DIM  256
#define EDGE_F  64
#define OUT_DIM 32
#define EDGE_OUT 64
#define NHEADS  8
#define HD      256   // NHEADS*OUT_DIM
#define ALPHA   0.2f
#define BN_EPS  1e-5f

#define NBINS 50432   // 197*256, >= N_NODES+1
#define NBLK  197

__device__ __forceinline__ float b2f(bf16 v){ return __bfloat162float(v); }
__device__ __forceinline__ bf16  f2b(float v){ return __float2bfloat16(v); }
__device__ __forceinline__ float lrelu(float x){ return x > 0.f ? x : ALPHA*x; }
__device__ __forceinline__ unsigned fenc(float f){ unsigned u=__float_as_uint(f); return (u&0x80000000u)? ~u : (u|0x80000000u); }
__device__ __forceinline__ float fdec(unsigned k){ return (k&0x80000000u)? __uint_as_float(k&0x7fffffffu) : __uint_as_float(~k); }

// dtype-adaptive load/store: F32=true -> fp32 buffer, else bf16 buffer
template<bool F32> __device__ __forceinline__ float LD(const void* p, long i){
  if constexpr (F32) return ((const float*)p)[i];
  else               return b2f(((const bf16*)p)[i]);
}
template<bool F32> __device__ __forceinline__ void ST(void* p, long i, float v){
  if constexpr (F32) ((float*)p)[i] = v;
  else               ((bf16*)p)[i] = f2b(v);
}
// edge-section base inside d_out: skip N*HD elements of the flag-selected dtype
template<bool F32> __device__ __forceinline__ void* ESEC(void* out){
  return (char*)out + (size_t)N_NODES*HD*(F32?4:2);
}

// ---------------- MFMA fragment helpers (16x16x32 bf16) ----------------
typedef __attribute__((ext_vector_type(8))) short bf16x8;
typedef __attribute__((ext_vector_type(4))) float f32x4;

union PackU { uint4 u; bf16x8 v; };
__device__ __forceinline__ bf16x8 as_frag(uint4 w){ PackU p; p.u = w; return p.v; }
__device__ __forceinline__ bf16x8 zero_frag(){ PackU p; p.u = make_uint4(0,0,0,0); return p.v; }

#define MFMA16(a,b,c) __builtin_amdgcn_mfma_f32_16x16x32_bf16(a,b,c,0,0,0)

// split 8 f32 into hi (truncated-top-16) and lo (bf16 of exact remainder)
__device__ __forceinline__ void split8(float4 a, float4 b, bf16x8& hi, bf16x8& lo){
  float v[8] = {a.x,a.y,a.z,a.w,b.x,b.y,b.z,b.w};
  unsigned hu[4], lu[4];
  #pragma unroll
  for(int i=0;i<4;i++){
    unsigned u0 = __float_as_uint(v[2*i]);
    unsigned u1 = __float_as_uint(v[2*i+1]);
    unsigned h0 = u0 & 0xffff0000u, h1 = u1 & 0xffff0000u;
    hu[i] = (u0>>16) | h1;
    float l0 = v[2*i]   - __uint_as_float(h0);
    float l1 = v[2*i+1] - __uint_as_float(h1);
    union { bf16 h; unsigned short s; } c0, c1; c0.h = f2b(l0); c1.h = f2b(l1);
    lu[i] = (unsigned)c0.s | ((unsigned)c1.s << 16);
  }
  PackU H,L;
  H.u = make_uint4(hu[0],hu[1],hu[2],hu[3]);
  L.u = make_uint4(lu[0],lu[1],lu[2],lu[3]);
  hi = H.v; lo = L.v;
}

// load 8 consecutive elements -> hi/lo A-fragment regs
template<bool F32> __device__ __forceinline__ void load_split(const void* p, long off, bf16x8& hi, bf16x8& lo){
  if constexpr(F32){
    const float* f = (const float*)p + off;
    float4 a = *(const float4*)f;
    float4 b = *(const float4*)(f+4);
    split8(a,b,hi,lo);
  } else {
    hi = as_frag(*(const uint4*)((const bf16*)p + off));
    lo = zero_frag();
  }
}

// ---- K0: input-dtype detector ----
__global__ __launch_bounds__(256) void k_detect(const unsigned short* __restrict__ u,
                                                int* __restrict__ flag){
  __shared__ int cnt;
  if(threadIdx.x==0) cnt=0;
  __syncthreads();
  int local=0;
  for(int i=threadIdx.x;i<8192;i+=256){
    int e = (u[i]>>7)&0xFF;
    if(e>=200) local++;
  }
  atomicAdd(&cnt, local);
  __syncthreads();
  if(threadIdx.x==0) *flag = (cnt>64) ? 1 : 0;   // 1 => buffers are fp32
}

// ---------------- CSR build: histogram + 2-level scan (dst only) ----------------
__global__ __launch_bounds__(256) void k_hist(const int* __restrict__ dst, int* __restrict__ cnt){
  int e = blockIdx.x*256 + threadIdx.x;
  if(e < N_EDGES){
    unsigned d = (unsigned)dst[e];
    if(d < N_NODES) atomicAdd(&cnt[d], 1);
  }
}
__global__ __launch_bounds__(256) void k_scan1(const int* __restrict__ cnt, int* __restrict__ rs,
                                               int* __restrict__ btot){
  __shared__ int s[256];
  int t = threadIdx.x; int i = blockIdx.x*256 + t;
  int v = cnt[i]; s[t] = v; __syncthreads();
  for(int off=1; off<256; off<<=1){
    int x = (t>=off) ? s[t-off] : 0; __syncthreads();
    s[t] += x; __syncthreads();
  }
  rs[i] = s[t] - v;
  if(t==255) btot[blockIdx.x] = s[t];
}
__global__ __launch_bounds__(256) void k_scan2(const int* __restrict__ btot, int* __restrict__ bsum){
  __shared__ int s[256];
  int t = threadIdx.x;
  int v = (t<NBLK) ? btot[t] : 0; s[t] = v; __syncthreads();
  for(int off=1; off<256; off<<=1){
    int x = (t>=off) ? s[t-off] : 0; __syncthreads();
    s[t] += x; __syncthreads();
  }
  if(t<NBLK) bsum[t] = s[t] - v;
}
__global__ __launch_bounds__(256) void k_scan3(int* __restrict__ rs, const int* __restrict__ bsum,
                                               int* __restrict__ cursor){
  int i = blockIdx.x*256 + threadIdx.x;
  int r = rs[i] + bsum[blockIdx.x];
  rs[i] = r; cursor[i] = r;
}

// ---------------- weight pack into MFMA B-fragment order (bf16) ----------
// element ((ks*NT+nt)*64+lane)*8+j  <-  W[ks*32 + (lane>>4)*8 + j][nt*16 + (lane&15)]
// sections (bf16 offsets): wn @0 (32768), we @32768 (4096), wf @36864 (8192),
//                          aw1 @45056 (2048)  -> total 47104
template<bool F32> __device__ void pack_body(const void* wn, const void* we, const void* wf,
                                             const void* aw1, unsigned short* out){
  int i = blockIdx.x*256 + threadIdx.x;
  if(i >= 47104) return;
  union { bf16 h; unsigned short s; } u;
  if(i < 45056){
    const void* srcp; int idx;
    if(i < 32768){ srcp = wn; idx = i; }
    else if(i < 36864){ srcp = we; idx = i - 32768; }
    else { srcp = wf; idx = i - 36864; }
    int j = idx & 7, lane = (idx>>3)&63, nt = (idx>>9)&3, ks = idx>>11;
    int k = ks*32 + ((lane>>4)<<3) + j;
    int n = (nt<<4) + (lane&15);
    u.h = f2b(LD<F32>(srcp, (long)k*EDGE_OUT + n));
  } else {
    int idx = i - 45056;           // ae_w1: 64x32, NT=2, KS=2
    int j = idx & 7, lane = (idx>>3)&63, nt = (idx>>9)&1, ks = idx>>10;
    int k = ks*32 + ((lane>>4)<<3) + j;
    int n = (nt<<4) + (lane&15);
    u.h = f2b(LD<F32>(aw1, (long)k*OUT_DIM + n));
  }
  out[i] = u.s;
}
__global__ __launch_bounds__(256) void k_pack_w(const void* wn, const void* we, const void* wf,
                                                const void* aw1, unsigned short* out,
                                                const int* flag){
  if(*flag) pack_body<true >(wn,we,wf,aw1,out);
  else      pack_body<false>(wn,we,wf,aw1,out);
}
// fc_w pack: K=256, Nout=256 (NT=16), 65536 elems
template<bool F32> __device__ void pack_fc_body(const void* w, unsigned short* out){
  int i = blockIdx.x*256 + threadIdx.x;
  int j = i&7, lane = (i>>3)&63, nt = (i>>9)&15, ks = i>>13;
  int k = ks*32 + ((lane>>4)<<3) + j;
  int n = (nt<<4) + (lane&15);
  union { bf16 h; unsigned short s; } u;
  u.h = f2b(LD<F32>(w, (long)k*HD + n));
  out[i] = u.s;
}
__global__ __launch_bounds__(256) void k_pack_fc(const void* w, unsigned short* out, const int* flag){
  if(*flag) pack_fc_body<true >(w,out);
  else      pack_fc_body<false>(w,out);
}

// ---------------- K1: ft = node_inputs @ fc_w via MFMA -> ftb (f32 workspace) -------
template<bool F32> __device__ void nproj_body(const void* x, const unsigned short* wpf, float* ft){
  const uint4* w4 = (const uint4*)wpf;
  int wid = threadIdx.x>>6, lane = threadIdx.x&63;
  int row16 = lane&15, kgrp = lane>>4;
  int r0 = blockIdx.x*64 + wid*16;
  long arow = r0 + row16; if(arow >= N_NODES) arow = N_NODES-1;
  f32x4 acc[16];
  #pragma unroll
  for(int nt=0;nt<16;nt++) acc[nt] = (f32x4){0.f,0.f,0.f,0.f};
  #pragma unroll 2
  for(int ks=0;ks<8;ks++){
    bf16x8 ah, al;
    load_split<F32>(x, arow*IN_DIM + ks*32 + kgrp*8, ah, al);
    const uint4* wb = w4 + (size_t)(ks*16)*64 + lane;
    #pragma unroll
    for(int nt=0;nt<16;nt++){
      bf16x8 b = as_frag(wb[nt*64]);
      if constexpr(F32) acc[nt] = MFMA16(al, b, acc[nt]);
      acc[nt] = MFMA16(ah, b, acc[nt]);
    }
  }
  #pragma unroll
  for(int nt=0;nt<16;nt++)
    #pragma unroll
    for(int j=0;j<4;j++){
      int r = r0 + kgrp*4 + j;
      if(r < N_NODES) ft[(long)r*HD + nt*16 + row16] = acc[nt][j];
    }
}
__global__ __launch_bounds__(256) void k_node_proj(const void* x, const unsigned short* wpf,
                                                   float* ft, const int* flag){
  if(*flag) nproj_body<true >(x,wpf,ft);
  else      nproj_body<false>(x,wpf,ft);
}

// ---------------- K2: a1/a2 per-(node,head) dots (ft is f32) ----------------
template<bool F32> __device__ void attn_body(const float* ft, const void* al, const void* ar,
                                             float* a1, float* a2){
  int gid = blockIdx.x*8 + (threadIdx.x>>5);
  int d   = threadIdx.x & 31;
  int h   = gid & 7;
  float v  = ft[(long)gid*OUT_DIM + d];
  float s1 = v * LD<F32>(al, h*OUT_DIM + d);
  float s2 = v * LD<F32>(ar, h*OUT_DIM + d);
  for(int o=16;o>0;o>>=1){ s1 += __shfl_down(s1,o,32); s2 += __shfl_down(s2,o,32); }
  if(d==0){ a1[gid]=s1; a2[gid]=s2; }
}
__global__ __launch_bounds__(256) void k_attn(const float* ft, const void* al, const void* ar,
                                              float* a1, float* a2, const int* flag){
  if(*flag) attn_body<true >(ft,al,ar,a1,a2);
  else      attn_body<false>(ft,al,ar,a1,a2);
}

// ---------------- K3: edge-attn via MFMA + wave-parallel head GEMM + CSR write ------
// 4 waves/block, 16 edges/wave (64 edges/block).
// GEMM1: h1 = lrelu(e_in @ ae_w1 + b1)  (K=64 -> 32 cols, MFMA, hi/lo split)
// GEMM2: s  = h1 @ ae_w2 + b2           (16x32 @ 32x8, VALU from transposed LDS tile)
// then av = lrelu(a1[src]+a2[dst]+s), CSR slot write, segment-max.
#define ST_STRIDE 20   // f32 stride of transposed per-wave tile st[col][row], float4-aligned

template<bool F32>
__device__ void edge_attn_body(const void* ein, const void* b1, const void* w2, const void* b2,
                               const float* a1, const float* a2,
                               const int* src, const int* dst,
                               int* cursor, unsigned short* psrc,
                               float* a_edge, unsigned* amax,
                               const unsigned short* wpack, float* sm){
  const uint4* aw1 = ((const uint4*)wpack) + 5632;   // 45056 bf16 / 8
  float* sw2f = sm;           // 256 (32x8)
  float* sb1  = sm + 256;     // 32
  float* sb2  = sm + 288;     // 8
  float* st   = sm + 296;     // 4 waves x 32 cols x ST_STRIDE
  int t = threadIdx.x;
  sw2f[t] = LD<F32>(w2, t);
  if(t<OUT_DIM) sb1[t] = LD<F32>(b1, t);
  if(t<NHEADS)  sb2[t] = LD<F32>(b2, t);
  __syncthreads();

  int wid = t>>6, lane = t&63;
  int row16 = lane&15, kgrp = lane>>4;
  int e0w = blockIdx.x*64 + wid*16;
  int e_a = e0w + row16;
  float* myst = st + wid*(32*ST_STRIDE);

  // ---- GEMM1: K=64 -> 32 cols ----
  f32x4 acc_h[2], acc_l[2];
  #pragma unroll
  for(int q=0;q<2;q++){ acc_h[q]=(f32x4){0.f,0.f,0.f,0.f}; acc_l[q]=(f32x4){0.f,0.f,0.f,0.f}; }
  long ebase = (long)e_a * EDGE_F;
  #pragma unroll
  for(int ks=0; ks<2; ks++){
    bf16x8 ah, al;
    load_split<F32>(ein, ebase + ks*32 + kgrp*8, ah, al);
    const uint4* wb = aw1 + (size_t)(ks*2)*64 + lane;
    #pragma unroll
    for(int nt=0; nt<2; nt++){
      bf16x8 bfr = as_frag(wb[nt*64]);
      acc_h[nt] = MFMA16(ah, bfr, acc_h[nt]);
      if constexpr(F32) acc_l[nt] = MFMA16(al, bfr, acc_l[nt]);
    }
  }
  // store transposed: st[col][row], rows kgrp*4..+3 contiguous -> float4
  #pragma unroll
  for(int nt=0; nt<2; nt++){
    int col = nt*16 + row16;
    float4 v;
    v.x = lrelu(acc_h[nt][0] + acc_l[nt][0] + sb1[col]);
    v.y = lrelu(acc_h[nt][1] + acc_l[nt][1] + sb1[col]);
    v.z = lrelu(acc_h[nt][2] + acc_l[nt][2] + sb1[col]);
    v.w = lrelu(acc_h[nt][3] + acc_l[nt][3] + sb1[col]);
    *(float4*)&myst[col*ST_STRIDE + kgrp*4] = v;
  }
  __syncthreads();

  // ---- GEMM2 + epilogue: each lane handles (r, h) and (r+8, h) ----
  int h = lane&7, r = lane>>3;
  float s0 = sb2[h], s1 = sb2[h];
  #pragma unroll 8
  for(int k=0;k<OUT_DIM;k++){
    float w = sw2f[k*NHEADS+h];
    s0 = fmaf(myst[k*ST_STRIDE + r],     w, s0);
    s1 = fmaf(myst[k*ST_STRIDE + r + 8], w, s1);
  }
  int ea0 = e0w + r, ea1 = e0w + r + 8;
  int sv0 = src[ea0], dv0 = dst[ea0];
  int sv1 = src[ea1], dv1 = dst[ea1];
  float av0 = lrelu(a1[sv0*NHEADS+h] + a2[dv0*NHEADS+h] + s0);   // TEMP==1
  float av1 = lrelu(a1[sv1*NHEADS+h] + a2[dv1*NHEADS+h] + s1);
  int pos0 = 0, pos1 = 0;
  if(h==0){
    pos0 = atomicAdd(&cursor[dv0], 1);
    pos1 = atomicAdd(&cursor[dv1], 1);
  }
  pos0 = __shfl(pos0, lane & 56, 64);
  pos1 = __shfl(pos1, lane & 56, 64);
  a_edge[(long)pos0*NHEADS + h] = av0;
  a_edge[(long)pos1*NHEADS + h] = av1;
  if(h==0){ psrc[pos0] = (unsigned short)sv0; psrc[pos1] = (unsigned short)sv1; }
  atomicMax(&amax[dv0*NHEADS+h], fenc(av0));
  atomicMax(&amax[dv1*NHEADS+h], fenc(av1));
}
__global__ __launch_bounds__(256) void k_edge_attn(const void* ein, const void* b1,
                                                   const void* w2, const void* b2,
                                                   const float* a1, const float* a2,
                                                   const int* src, const int* dst,
                                                   int* cursor, unsigned short* psrc,
                                                   float* a_edge, unsigned* amax,
                                                   const unsigned short* wpack, const int* flag){
  extern __shared__ float smemf[];
  if(*flag) edge_attn_body<true >(ein,b1,w2,b2,a1,a2,src,dst,cursor,psrc,a_edge,amax,wpack,smemf);
  else      edge_attn_body<false>(ein,b1,w2,b2,a1,a2,src,dst,cursor,psrc,a_edge,amax,wpack,smemf);
}

// ---------------- K4: fused CSR aggregation + softmax + residual + lrelu + BN stats --
template<bool F32> __device__ void agg_body(const int* rs, const unsigned short* psrc,
                                            const float* a_edge, const unsigned* amax,
                                            const float* ft, const void* xin, void* xout,
                                            double* dstats, double* sm){
  int wid = threadIdx.x>>6, lane = threadIdx.x&63;
  int gw = blockIdx.x*4 + wid, nw = gridDim.x*4;
  int h0 = lane>>5;
  double s4[4]={0,0,0,0}, q4[4]={0,0,0,0};
  for(int n=gw; n<N_NODES; n+=nw){
    int b0 = rs[n], b1 = rs[n+1];
    if(b1 > N_EDGES) b1 = N_EDGES;
    if(b0 > b1) b0 = b1;
    float m = (lane<8) ? fdec(amax[n*NHEADS+lane]) : 0.f;
    float zl = 0.f;
    float acc[4] = {0,0,0,0};
    for(int i=b0;i<b1;++i){
      float av = 0.f;
      if(lane<8){ av = __expf(a_edge[(long)i*NHEADS+lane] - m); zl += av; }
      int sv = psrc[i];
      const float* fr = ft + (long)sv*HD;
      #pragma unroll
      for(int q=0;q<4;q++){
        float a = __shfl(av, h0 + 2*q, 64);
        acc[q] = fmaf(a, fr[lane + 64*q], acc[q]);
      }
    }
    #pragma unroll
    for(int q=0;q<4;q++){
      float z = __shfl(zl, h0 + 2*q, 64);
      float zs = (z==0.f) ? 1.f : z;
      int c = lane + 64*q;
      float xv = lrelu(acc[q]/zs + LD<F32>(xin,(long)n*HD + c));
      ST<F32>(xout,(long)n*HD + c, xv);
      s4[q] += xv; q4[q] += (double)xv*(double)xv;
    }
  }
  double* ls = sm; double* lq = sm + 256;
  for(int w=0;w<4;w++){
    if(wid==w){
      #pragma unroll
      for(int q=0;q<4;q++){
        int c = lane + 64*q;
        if(w==0){ ls[c]=s4[q]; lq[c]=q4[q]; }
        else    { ls[c]+=s4[q]; lq[c]+=q4[q]; }
      }
    }
    __syncthreads();
  }
  int t = threadIdx.x;
  unsafeAtomicAdd(&dstats[t],    ls[t]);
  unsafeAtomicAdd(&dstats[HD+t], lq[t]);
}
__global__ __launch_bounds__(256) void k_agg(const int* rs, const unsigned short* psrc,
                                             const float* a_edge, const unsigned* amax,
                                             const float* ft, const void* xin, void* xout,
                                             double* dstats, const int* flag){
  extern __shared__ double smemd[];
  if(*flag) agg_body<true >(rs,psrc,a_edge,amax,ft,xin,xout,dstats,smemd);
  else      agg_body<false>(rs,psrc,a_edge,amax,ft,xin,xout,dstats,smemd);
}

// ---------------- BN params from double sums ----------------
template<bool F32> __device__ void bn_params_body(const double* dstats, const void* g,
                                                  const void* b, float* scsh, int C, double invM){
  int t = threadIdx.x;
  if(t>=C) return;
  double mu  = dstats[t]*invM;
  double var = dstats[C+t]*invM - mu*mu;
  if(var < 0.0) var = 0.0;
  float sc = LD<F32>(g,t) * rsqrtf((float)var + BN_EPS);
  scsh[t]   = sc;
  scsh[C+t] = LD<F32>(b,t) - (float)mu*sc;
}
__global__ void k_bn_params(const double* dstats, const void* g, const void* b,
                            float* scsh, int C, double invM, const int* flag){
  if(*flag) bn_params_body<true >(dstats,g,b,scsh,C,invM);
  else      bn_params_body<false>(dstats,g,b,scsh,C,invM);
}

// ---------------- K6: node BN apply, in place on d_out node section ----------------
template<bool F32> __device__ void node_apply_body(void* x, const float* scsh){
  int t = threadIdx.x;
  float sc = scsh[t], sh = scsh[HD+t];
  for(long i=(long)blockIdx.x*256+t; i<(long)N_NODES*HD; i+=(long)gridDim.x*256){
    ST<F32>(x, i, fmaf(LD<F32>(x,i), sc, sh));
  }
}
__global__ __launch_bounds__(256) void k_node_apply(void* x, const float* scsh, const int* flag){
  if(*flag) node_apply_body<true >(x,scsh);
  else      node_apply_body<false>(x,scsh);
}

// ---------------- K6c: P/Q = node_out @ Wn_top / Wn_bot  (MFMA, per NODE) ----------
template<bool F32> __device__ void pq_body(const void* nodeb, const unsigned short* wpack,
                                           float* P, float* Q){
  const uint4* wn4 = (const uint4*)wpack;
  int wid = threadIdx.x>>6, lane = threadIdx.x&63;
  int row16 = lane&15, kgrp = lane>>4;
  int r0 = blockIdx.x*64 + wid*16;
  long arow = r0 + row16; if(arow >= N_NODES) arow = N_NODES-1;
  f32x4 pacc[4], qacc[4];
  #pragma unroll
  for(int nt=0;nt<4;nt++){ pacc[nt]=(f32x4){0.f,0.f,0.f,0.f}; qacc[nt]=(f32x4){0.f,0.f,0.f,0.f}; }
  #pragma unroll 2
  for(int ks=0;ks<8;ks++){
    bf16x8 ah, al;
    load_split<F32>(nodeb, arow*HD + ks*32 + kgrp*8, ah, al);
    const uint4* wbP = wn4 + (size_t)(ks*4)*64 + lane;
    const uint4* wbQ = wn4 + (size_t)((8+ks)*4)*64 + lane;
    #pragma unroll
    for(int nt=0;nt<4;nt++){
      bf16x8 bP = as_frag(wbP[nt*64]);
      bf16x8 bQ = as_frag(wbQ[nt*64]);
      pacc[nt] = MFMA16(ah, bP, pacc[nt]);
      qacc[nt] = MFMA16(ah, bQ, qacc[nt]);
      if constexpr(F32){
        pacc[nt] = MFMA16(al, bP, pacc[nt]);
        qacc[nt] = MFMA16(al, bQ, qacc[nt]);
      }
    }
  }
  #pragma unroll
  for(int nt=0;nt<4;nt++)
    #pragma unroll
    for(int j=0;j<4;j++){
      int r = r0 + kgrp*4 + j;
      if(r < N_NODES){
        P[(long)r*64 + nt*16 + row16] = pacc[nt][j];
        Q[(long)r*64 + nt*16 + row16] = qacc[nt][j];
      }
    }
}
__global__ __launch_bounds__(256) void k_pq(const void* nodeb, const unsigned short* wpack,
                                            float* P, float* Q, const int* flag){
  if(*flag) pq_body<true >(nodeb,wpack,P,Q);
  else      pq_body<false>(nodeb,wpack,P,Q);
}

// ---------------- K7: fused edge update via MFMA (P/Q-factored) ----------------
#define EF_LROW 68   // padded LDS row stride (f32) for the 16x64 per-wave ef tile

template<bool F32>
__device__ void edge_update_body(const float* P, const float* Q, const void* edge_in,
                                 const int* src, const int* dst,
                                 const unsigned short* wpack,
                                 void* d_out, float* lds){
  void* edge_x = ESEC<F32>(d_out);
  const uint4* we4 = ((const uint4*)wpack) + 4096;
  const uint4* wf4 = ((const uint4*)wpack) + 4608;
  int wid   = threadIdx.x >> 6;
  int lane  = threadIdx.x & 63;
  int row16 = lane & 15;
  int kgrp  = lane >> 4;
  int e0  = blockIdx.x*64 + wid*16;
  int e_a = e0 + row16;
  int nsrc = src[e_a], ndst = dst[e_a];
  float* myl = lds + wid*(16*EF_LROW);

  f32x4 acc_h[4], acc_l[4];
  #pragma unroll
  for(int t=0;t<4;t++){ acc_h[t]=(f32x4){0.f,0.f,0.f,0.f}; acc_l[t]=(f32x4){0.f,0.f,0.f,0.f}; }

  // ---- ef GEMM: K = 64 ----
  long ebase = (long)e_a * EDGE_F;
  #pragma unroll
  for(int ks=0; ks<2; ks++){
    bf16x8 ah, al;
    load_split<F32>(edge_in, ebase + ks*32 + kgrp*8, ah, al);
    const uint4* wb = we4 + (size_t)(ks*4)*64 + lane;
    #pragma unroll
    for(int nt=0; nt<4; nt++){
      bf16x8 bfr = as_frag(wb[nt*64]);
      acc_h[nt] = MFMA16(ah, bfr, acc_h[nt]);
      if constexpr(F32) acc_l[nt] = MFMA16(al, bfr, acc_l[nt]);
    }
  }
  #pragma unroll
  for(int nt=0; nt<4; nt++)
    #pragma unroll
    for(int j=0;j<4;j++)
      myl[(kgrp*4+j)*EF_LROW + nt*16 + row16] = lrelu(acc_h[nt][j] + acc_l[nt][j]);

  __syncthreads();   // ef C-layout -> A-layout redistribution

  // ---- final GEMM: K = 128 (k 0..63 = nf from P/Q gather, k 64..127 = ef from LDS) ----
  #pragma unroll
  for(int t=0;t<4;t++){ acc_h[t]=(f32x4){0.f,0.f,0.f,0.f}; acc_l[t]=(f32x4){0.f,0.f,0.f,0.f}; }
  #pragma unroll
  for(int ks=0; ks<2; ks++){
    const float* pp = P + (long)nsrc*64 + ks*32 + kgrp*8;
    const float* qq = Q + (long)ndst*64 + ks*32 + kgrp*8;
    float4 p0 = *(const float4*)pp, p1 = *(const float4*)(pp+4);
    float4 q0 = *(const float4*)qq, q1 = *(const float4*)(qq+4);
    float4 v0, v1;
    v0.x = lrelu(p0.x+q0.x); v0.y = lrelu(p0.y+q0.y);
    v0.z = lrelu(p0.z+q0.z); v0.w = lrelu(p0.w+q0.w);
    v1.x = lrelu(p1.x+q1.x); v1.y = lrelu(p1.y+q1.y);
    v1.z = lrelu(p1.z+q1.z); v1.w = lrelu(p1.w+q1.w);
    bf16x8 ah, al; split8(v0, v1, ah, al);
    const uint4* wb = wf4 + (size_t)(ks*4)*64 + lane;
    #pragma unroll
    for(int nt=0; nt<4; nt++){
      bf16x8 bfr = as_frag(wb[nt*64]);
      acc_h[nt] = MFMA16(ah, bfr, acc_h[nt]);
      acc_l[nt] = MFMA16(al, bfr, acc_l[nt]);
    }
  }
  #pragma unroll
  for(int ks=2; ks<4; ks++){
    const float* ap = myl + row16*EF_LROW + (ks-2)*32 + kgrp*8;
    float4 a0 = *(const float4*)ap;
    float4 a1 = *(const float4*)(ap+4);
    bf16x8 ah, al; split8(a0, a1, ah, al);
    const uint4* wb = wf4 + (size_t)(ks*4)*64 + lane;
    #pragma unroll
    for(int nt=0; nt<4; nt++){
      bf16x8 bfr = as_frag(wb[nt*64]);
      acc_h[nt] = MFMA16(ah, bfr, acc_h[nt]);
      acc_l[nt] = MFMA16(al, bfr, acc_l[nt]);
    }
  }
  #pragma unroll
  for(int nt=0; nt<4; nt++)
    #pragma unroll
    for(int j=0;j<4;j++){
      long e = e0 + kgrp*4 + j;
      int  c = nt*16 + row16;
      float res = LD<F32>(edge_in, e*EDGE_OUT + c);
      ST<F32>(edge_x, e*EDGE_OUT + c, lrelu(acc_h[nt][j] + acc_l[nt][j] + res));
    }
}
__global__ __launch_bounds__(256) void k_edge_update(const float* P, const float* Q,
                                                     const void* edge_in,
                                                     const int* src, const int* dst,
                                                     const unsigned short* wpack,
                                                     void* d_out, const int* flag){
  extern __shared__ float smemf[];
  if(*flag) edge_update_body<true >(P,Q,edge_in,src,dst,wpack,d_out,smemf);
  else      edge_update_body<false>(P,Q,edge_in,src,dst,wpack,d_out,smemf);
}

// ---------------- K8: edge column stats ----------------
template<bool F32> __device__ void edge_stats_body(void* d_out, double* dstats, double* sm){
  const void* ex = ESEC<F32>(d_out);
  double* ls = sm; double* lq = sm+256;
  int t = threadIdx.x;
  int c = t & 63, r0 = t >> 6;
  double s=0.0, q=0.0;
  for(long i=(long)(blockIdx.x*4 + r0)*64 + c; i < (long)N_EDGES*EDGE_OUT; i += (long)gridDim.x*4*64){
    float x = LD<F32>(ex, i);
    s += x; q += (double)x*(double)x;
  }
  ls[t]=s; lq[t]=q;
  __syncthreads();
  if(t<64){
    double ss = ls[t]+ls[t+64]+ls[t+128]+ls[t+192];
    double qq = lq[t]+lq[t+64]+lq[t+128]+lq[t+192];
    unsafeAtomicAdd(&dstats[t], ss);
    unsafeAtomicAdd(&dstats[64+t], qq);
  }
}
__global__ __launch_bounds__(256) void k_edge_stats(void* d_out, double* dstats, const int* flag){
  extern __shared__ double smemd[];
  if(*flag) edge_stats_body<true >(d_out,dstats,smemd);
  else      edge_stats_body<false>(d_out,dstats,smemd);
}

// ---------------- K9: edge BN apply, in place on d_out edge section ----------------
template<bool F32> __device__ void edge_apply_body(void* d_out, const float* scsh){
  void* ex = ESEC<F32>(d_out);
  int t = threadIdx.x;
  int c = t & 63;
  float sc = scsh[c], sh = scsh[64+c];
  for(long i=(long)blockIdx.x*256+t; i<(long)N_EDGES*EDGE_OUT; i+=(long)gridDim.x*256){
    ST<F32>(ex, i, fmaf(LD<F32>(ex,i), sc, sh));
  }
}
__global__ __launch_bounds__(256) void k_edge_apply(void* d_out, const float* scsh, const int* flag){
  if(*flag) edge_apply_body<true >(d_out,scsh);
  else      edge_apply_body<false>(d_out,scsh);
}

extern "C" void kernel_launch(void* const* d_in, const int* in_sizes, int n_in,
                              void* d_out, int out_size, void* d_ws, size_t ws_size,
                              hipStream_t stream){
  const void* node_in    = d_in[0];
  const void* edge_in    = d_in[1];
  const void* fc_w       = d_in[2];
  const void* attn_l     = d_in[3];
  const void* attn_r     = d_in[4];
  const void* ae_w1      = d_in[5];
  const void* ae_b1      = d_in[6];
  const void* ae_w2      = d_in[7];
  const void* ae_b2      = d_in[8];
  const void* bn_n_g     = d_in[9];
  const void* bn_n_b     = d_in[10];
  const void* eu_node_w  = d_in[11];
  const void* eu_edge_w  = d_in[12];
  const void* eu_final_w = d_in[13];
  const void* bn_e_g     = d_in[14];
  const void* bn_e_b     = d_in[15];
  const int*  src        = (const int*)d_in[16];
  const int*  dst        = (const int*)d_in[17];

  // ---- workspace, all inside d_ws (~70.28 MB total; proven envelope >= 70.41 MB) ----
  char* base = (char*)d_ws;
  double*   dstats_n = (double*)base;                 // 512 dbl
  double*   dstats_e = (double*)(base + 4096);        // 128 dbl
  float*    scsh_n   = (float*)(base + 5120);         // 512 f
  float*    scsh_e   = (float*)(base + 7168);         // 128 f
  int*      flag     = (int*)(base + 7680);
  char*     big      = base + 8192;
  float*    ftb      = (float*)big;                   // N*HD f32 = 51.2MB (always f32)
  float*    Pb       = (float*)big;                   // N*64 f32 = 12.8MB (reuses ftb after k_agg)
  float*    Qb       = (float*)(big + 12800000);      // N*64 f32 = 12.8MB
  float*    a_edge   = (float*)(big + 51200000);      // E*8 f32 (CSR order) = 12.8MB
  float*    a1       = (float*)(big + 64000000);      // N*8 f32
  float*    a2       = (float*)(big + 65600000);      // N*8 f32
  unsigned* amax     = (unsigned*)(big + 67200000);   // N*8 u32 -> ends 68.8MB
  unsigned short* wpack_eu = (unsigned short*)(big + 68800000);  // 94.2KB (incl. aw1)
  unsigned short* wpack_fc = (unsigned short*)(big + 68900000);  // 128KB
  int*      rsb      = (int*)(big + 69040000);        // NBINS ints (202KB)
  int*      cursor   = (int*)(big + 69250000);        // NBINS ints (doubles as histogram)
  int*      btot     = (int*)(big + 69460000);        // NBLK ints
  int*      bsum     = (int*)(big + 69461024);        // NBLK ints
  unsigned short* psrc = (unsigned short*)(big + 69470000); // E u16 (0.8MB) -> ends 70.27MB

  hipMemsetAsync(dstats_n, 0, 640*sizeof(double), stream);
  hipMemsetAsync(amax, 0, (size_t)N_NODES*NHEADS*sizeof(unsigned), stream);
  hipMemsetAsync(cursor, 0, NBINS*sizeof(int), stream);

  k_detect<<<1, 256, 0, stream>>>((const unsigned short*)node_in, flag);
  // CSR build (flag-independent)
  k_hist <<<(N_EDGES+255)/256, 256, 0, stream>>>(dst, cursor);
  k_scan1<<<NBLK, 256, 0, stream>>>(cursor, rsb, btot);
  k_scan2<<<1, 256, 0, stream>>>(btot, bsum);
  k_scan3<<<NBLK, 256, 0, stream>>>(rsb, bsum, cursor);
  // weight packs
  k_pack_fc<<<256, 256, 0, stream>>>(fc_w, wpack_fc, flag);
  k_pack_w<<<184, 256, 0, stream>>>(eu_node_w, eu_edge_w, eu_final_w, ae_w1, wpack_eu, flag);
  // node projection (MFMA) + attention scalars
  k_node_proj<<<(N_NODES+63)/64, 256, 0, stream>>>(node_in, wpack_fc, ftb, flag);
  k_attn<<<N_NODES*NHEADS/8, 256, 0, stream>>>(ftb, attn_l, attn_r, a1, a2, flag);
  // edge attention (MFMA) -> CSR slots + segment max
  k_edge_attn<<<N_EDGES/64, 256, (296 + 4*32*ST_STRIDE)*4, stream>>>(
      edge_in, ae_b1, ae_w2, ae_b2, a1, a2, src, dst, cursor, psrc,
      a_edge, amax, wpack_eu, flag);
  // fused softmax + aggregation + residual + lrelu + BN stats (no atomic scatter)
  k_agg<<<960, 256, 4096, stream>>>(rsb, psrc, a_edge, amax, ftb, node_in, d_out,
                                    dstats_n, flag);
  k_bn_params<<<1, 256, 0, stream>>>(dstats_n, bn_n_g, bn_n_b, scsh_n, HD, 1.0/N_NODES, flag);
  k_node_apply<<<2048, 256, 0, stream>>>(d_out, scsh_n, flag);
  // per-node P/Q projection (ftb is dead after k_agg; reuse its space)
  k_pq<<<(N_NODES+63)/64, 256, 0, stream>>>(d_out, wpack_eu, Pb, Qb, flag);
  // edge update (MFMA, P/Q-factored) + BN
  k_edge_update<<<N_EDGES/64, 256, 4*16*EF_LROW*4, stream>>>(Pb, Qb, edge_in, src, dst,
                                                             wpack_eu, d_out, flag);
  k_edge_stats<<<512, 256, 4096, stream>>>(d_out, dstats_e, flag);
  k_bn_params<<<1, 256, 0, stream>>>(dstats_e, bn_e_g, bn_e_b, scsh_e, EDGE_OUT, 1.0/N_EDGES, flag);
  k_edge_apply<<<2048, 256, 0, stream>>>(d_out, scsh_e, flag);
  (void)ws_size; (void)out_size; (void)n_in; (void)in_sizes;
}

// Round 6
// 805.435 us; speedup vs baseline: 3.9709x; 1.0263x over previous
//
#include <hip/hip_runtime.h>
#include <hip/hip_bf16.h>

typedef __hip_bfloat16 bf16;

#define N_NODES 50000
#define N_EDGES 400000
#define IN_DIM  256
#define EDGE_F  64
#define OUT_DIM 32
#define EDGE_OUT 64
#define NHEADS  8
#define HD      256   // NHEADS*OUT_DIM
#define ALPHA   0.2f
#define BN_EPS  1e-5f

#define NBINS 50432   // 197*256, >= N_NODES+1
#define NBLK  197

__device__ __forceinline__ float b2f(bf16 v){ return __bfloat162float(v); }
__device__ __forceinline__ bf16  f2b(float v){ return __float2bfloat16(v); }
__device__ __forceinline__ float lrelu(float x){ return x > 0.f ? x : ALPHA*x; }
__device__ __forceinline__ unsigned fenc(float f){ unsigned u=__float_as_uint(f); return (u&0x80000000u)? ~u : (u|0x80000000u); }
__device__ __forceinline__ float fdec(unsigned k){ return (k&0x80000000u)? __uint_as_float(k&0x7fffffffu) : __uint_as_float(~k); }

// dtype-adaptive load/store: F32=true -> fp32 buffer, else bf16 buffer
template<bool F32> __device__ __forceinline__ float LD(const void* p, long i){
  if constexpr (F32) return ((const float*)p)[i];
  else               return b2f(((const bf16*)p)[i]);
}
template<bool F32> __device__ __forceinline__ void ST(void* p, long i, float v){
  if constexpr (F32) ((float*)p)[i] = v;
  else               ((bf16*)p)[i] = f2b(v);
}
// edge-section base inside d_out: skip N*HD elements of the flag-selected dtype
template<bool F32> __device__ __forceinline__ void* ESEC(void* out){
  return (char*)out + (size_t)N_NODES*HD*(F32?4:2);
}

// ---------------- MFMA fragment helpers (16x16x32 bf16) ----------------
typedef __attribute__((ext_vector_type(8))) short bf16x8;
typedef __attribute__((ext_vector_type(4))) float f32x4;

union PackU { uint4 u; bf16x8 v; };
__device__ __forceinline__ bf16x8 as_frag(uint4 w){ PackU p; p.u = w; return p.v; }
__device__ __forceinline__ bf16x8 zero_frag(){ PackU p; p.u = make_uint4(0,0,0,0); return p.v; }

#define MFMA16(a,b,c) __builtin_amdgcn_mfma_f32_16x16x32_bf16(a,b,c,0,0,0)

// split 8 f32 into hi (truncated-top-16) and lo (bf16 of exact remainder)
__device__ __forceinline__ void split8(float4 a, float4 b, bf16x8& hi, bf16x8& lo){
  float v[8] = {a.x,a.y,a.z,a.w,b.x,b.y,b.z,b.w};
  unsigned hu[4], lu[4];
  #pragma unroll
  for(int i=0;i<4;i++){
    unsigned u0 = __float_as_uint(v[2*i]);
    unsigned u1 = __float_as_uint(v[2*i+1]);
    unsigned h0 = u0 & 0xffff0000u, h1 = u1 & 0xffff0000u;
    hu[i] = (u0>>16) | h1;
    float l0 = v[2*i]   - __uint_as_float(h0);
    float l1 = v[2*i+1] - __uint_as_float(h1);
    union { bf16 h; unsigned short s; } c0, c1; c0.h = f2b(l0); c1.h = f2b(l1);
    lu[i] = (unsigned)c0.s | ((unsigned)c1.s << 16);
  }
  PackU H,L;
  H.u = make_uint4(hu[0],hu[1],hu[2],hu[3]);
  L.u = make_uint4(lu[0],lu[1],lu[2],lu[3]);
  hi = H.v; lo = L.v;
}

// load 8 consecutive elements -> hi/lo A-fragment regs
template<bool F32> __device__ __forceinline__ void load_split(const void* p, long off, bf16x8& hi, bf16x8& lo){
  if constexpr(F32){
    const float* f = (const float*)p + off;
    float4 a = *(const float4*)f;
    float4 b = *(const float4*)(f+4);
    split8(a,b,hi,lo);
  } else {
    hi = as_frag(*(const uint4*)((const bf16*)p + off));
    lo = zero_frag();
  }
}

// ---- K0: input-dtype detector ----
__global__ __launch_bounds__(256) void k_detect(const unsigned short* __restrict__ u,
                                                int* __restrict__ flag){
  __shared__ int cnt;
  if(threadIdx.x==0) cnt=0;
  __syncthreads();
  int local=0;
  for(int i=threadIdx.x;i<8192;i+=256){
    int e = (u[i]>>7)&0xFF;
    if(e>=200) local++;
  }
  atomicAdd(&cnt, local);
  __syncthreads();
  if(threadIdx.x==0) *flag = (cnt>64) ? 1 : 0;   // 1 => buffers are fp32
}

// ---------------- CSR build: histogram + 2-level scan (dst only) ----------------
__global__ __launch_bounds__(256) void k_hist(const int* __restrict__ dst, int* __restrict__ cnt){
  int e = blockIdx.x*256 + threadIdx.x;
  if(e < N_EDGES){
    unsigned d = (unsigned)dst[e];
    if(d < N_NODES) atomicAdd(&cnt[d], 1);
  }
}
__global__ __launch_bounds__(256) void k_scan1(const int* __restrict__ cnt, int* __restrict__ rs,
                                               int* __restrict__ btot){
  __shared__ int s[256];
  int t = threadIdx.x; int i = blockIdx.x*256 + t;
  int v = cnt[i]; s[t] = v; __syncthreads();
  for(int off=1; off<256; off<<=1){
    int x = (t>=off) ? s[t-off] : 0; __syncthreads();
    s[t] += x; __syncthreads();
  }
  rs[i] = s[t] - v;
  if(t==255) btot[blockIdx.x] = s[t];
}
__global__ __launch_bounds__(256) void k_scan2(const int* __restrict__ btot, int* __restrict__ bsum){
  __shared__ int s[256];
  int t = threadIdx.x;
  int v = (t<NBLK) ? btot[t] : 0; s[t] = v; __syncthreads();
  for(int off=1; off<256; off<<=1){
    int x = (t>=off) ? s[t-off] : 0; __syncthreads();
    s[t] += x; __syncthreads();
  }
  if(t<NBLK) bsum[t] = s[t] - v;
}
__global__ __launch_bounds__(256) void k_scan3(int* __restrict__ rs, const int* __restrict__ bsum,
                                               int* __restrict__ cursor){
  int i = blockIdx.x*256 + threadIdx.x;
  int r = rs[i] + bsum[blockIdx.x];
  rs[i] = r; cursor[i] = r;
}

// ---------------- weight pack into MFMA B-fragment order (bf16) ----------
// element ((ks*NT+nt)*64+lane)*8+j  <-  W[ks*32 + (lane>>4)*8 + j][nt*16 + (lane&15)]
// sections (bf16 offsets): wn @0 (32768), we @32768 (4096), wf @36864 (8192),
//                          aw1 @45056 (2048)  -> total 47104
template<bool F32> __device__ void pack_body(const void* wn, const void* we, const void* wf,
                                             const void* aw1, unsigned short* out){
  int i = blockIdx.x*256 + threadIdx.x;
  if(i >= 47104) return;
  union { bf16 h; unsigned short s; } u;
  if(i < 45056){
    const void* srcp; int idx;
    if(i < 32768){ srcp = wn; idx = i; }
    else if(i < 36864){ srcp = we; idx = i - 32768; }
    else { srcp = wf; idx = i - 36864; }
    int j = idx & 7, lane = (idx>>3)&63, nt = (idx>>9)&3, ks = idx>>11;
    int k = ks*32 + ((lane>>4)<<3) + j;
    int n = (nt<<4) + (lane&15);
    u.h = f2b(LD<F32>(srcp, (long)k*EDGE_OUT + n));
  } else {
    int idx = i - 45056;           // ae_w1: 64x32, NT=2, KS=2
    int j = idx & 7, lane = (idx>>3)&63, nt = (idx>>9)&1, ks = idx>>10;
    int k = ks*32 + ((lane>>4)<<3) + j;
    int n = (nt<<4) + (lane&15);
    u.h = f2b(LD<F32>(aw1, (long)k*OUT_DIM + n));
  }
  out[i] = u.s;
}
__global__ __launch_bounds__(256) void k_pack_w(const void* wn, const void* we, const void* wf,
                                                const void* aw1, unsigned short* out,
                                                const int* flag){
  if(*flag) pack_body<true >(wn,we,wf,aw1,out);
  else      pack_body<false>(wn,we,wf,aw1,out);
}
// fc_w pack: K=256, Nout=256 (NT=16), 65536 elems
template<bool F32> __device__ void pack_fc_body(const void* w, unsigned short* out){
  int i = blockIdx.x*256 + threadIdx.x;
  int j = i&7, lane = (i>>3)&63, nt = (i>>9)&15, ks = i>>13;
  int k = ks*32 + ((lane>>4)<<3) + j;
  int n = (nt<<4) + (lane&15);
  union { bf16 h; unsigned short s; } u;
  u.h = f2b(LD<F32>(w, (long)k*HD + n));
  out[i] = u.s;
}
__global__ __launch_bounds__(256) void k_pack_fc(const void* w, unsigned short* out, const int* flag){
  if(*flag) pack_fc_body<true >(w,out);
  else      pack_fc_body<false>(w,out);
}

// ---------------- K1: ft = node_inputs @ fc_w via MFMA -> ftb (f32 workspace) -------
template<bool F32> __device__ void nproj_body(const void* x, const unsigned short* wpf, float* ft){
  const uint4* w4 = (const uint4*)wpf;
  int wid = threadIdx.x>>6, lane = threadIdx.x&63;
  int row16 = lane&15, kgrp = lane>>4;
  int r0 = blockIdx.x*64 + wid*16;
  long arow = r0 + row16; if(arow >= N_NODES) arow = N_NODES-1;
  f32x4 acc[16];
  #pragma unroll
  for(int nt=0;nt<16;nt++) acc[nt] = (f32x4){0.f,0.f,0.f,0.f};
  #pragma unroll 2
  for(int ks=0;ks<8;ks++){
    bf16x8 ah, al;
    load_split<F32>(x, arow*IN_DIM + ks*32 + kgrp*8, ah, al);
    const uint4* wb = w4 + (size_t)(ks*16)*64 + lane;
    #pragma unroll
    for(int nt=0;nt<16;nt++){
      bf16x8 b = as_frag(wb[nt*64]);
      if constexpr(F32) acc[nt] = MFMA16(al, b, acc[nt]);
      acc[nt] = MFMA16(ah, b, acc[nt]);
    }
  }
  #pragma unroll
  for(int nt=0;nt<16;nt++)
    #pragma unroll
    for(int j=0;j<4;j++){
      int r = r0 + kgrp*4 + j;
      if(r < N_NODES) ft[(long)r*HD + nt*16 + row16] = acc[nt][j];
    }
}
__global__ __launch_bounds__(256) void k_node_proj(const void* x, const unsigned short* wpf,
                                                   float* ft, const int* flag){
  if(*flag) nproj_body<true >(x,wpf,ft);
  else      nproj_body<false>(x,wpf,ft);
}

// ---------------- K2: a1/a2 per-(node,head) dots (ft is f32) ----------------
template<bool F32> __device__ void attn_body(const float* ft, const void* al, const void* ar,
                                             float* a1, float* a2){
  int gid = blockIdx.x*8 + (threadIdx.x>>5);
  int d   = threadIdx.x & 31;
  int h   = gid & 7;
  float v  = ft[(long)gid*OUT_DIM + d];
  float s1 = v * LD<F32>(al, h*OUT_DIM + d);
  float s2 = v * LD<F32>(ar, h*OUT_DIM + d);
  for(int o=16;o>0;o>>=1){ s1 += __shfl_down(s1,o,32); s2 += __shfl_down(s2,o,32); }
  if(d==0){ a1[gid]=s1; a2[gid]=s2; }
}
__global__ __launch_bounds__(256) void k_attn(const float* ft, const void* al, const void* ar,
                                              float* a1, float* a2, const int* flag){
  if(*flag) attn_body<true >(ft,al,ar,a1,a2);
  else      attn_body<false>(ft,al,ar,a1,a2);
}

// ---------------- K3: edge-attn via MFMA + wave-parallel head GEMM + CSR write ------
#define ST_STRIDE 20   // f32 stride of transposed per-wave tile st[col][row], float4-aligned

template<bool F32>
__device__ void edge_attn_body(const void* ein, const void* b1, const void* w2, const void* b2,
                               const float* a1, const float* a2,
                               const int* src, const int* dst,
                               int* cursor, unsigned short* psrc,
                               float* a_edge, unsigned* amax,
                               const unsigned short* wpack, float* sm){
  const uint4* aw1 = ((const uint4*)wpack) + 5632;   // 45056 bf16 / 8
  float* sw2f = sm;           // 256 (32x8)
  float* sb1  = sm + 256;     // 32
  float* sb2  = sm + 288;     // 8
  float* st   = sm + 296;     // 4 waves x 32 cols x ST_STRIDE
  int t = threadIdx.x;
  sw2f[t] = LD<F32>(w2, t);
  if(t<OUT_DIM) sb1[t] = LD<F32>(b1, t);
  if(t<NHEADS)  sb2[t] = LD<F32>(b2, t);
  __syncthreads();

  int wid = t>>6, lane = t&63;
  int row16 = lane&15, kgrp = lane>>4;
  int e0w = blockIdx.x*64 + wid*16;
  int e_a = e0w + row16;
  float* myst = st + wid*(32*ST_STRIDE);

  // ---- GEMM1: K=64 -> 32 cols ----
  f32x4 acc_h[2], acc_l[2];
  #pragma unroll
  for(int q=0;q<2;q++){ acc_h[q]=(f32x4){0.f,0.f,0.f,0.f}; acc_l[q]=(f32x4){0.f,0.f,0.f,0.f}; }
  long ebase = (long)e_a * EDGE_F;
  #pragma unroll
  for(int ks=0; ks<2; ks++){
    bf16x8 ah, al;
    load_split<F32>(ein, ebase + ks*32 + kgrp*8, ah, al);
    const uint4* wb = aw1 + (size_t)(ks*2)*64 + lane;
    #pragma unroll
    for(int nt=0; nt<2; nt++){
      bf16x8 bfr = as_frag(wb[nt*64]);
      acc_h[nt] = MFMA16(ah, bfr, acc_h[nt]);
      if constexpr(F32) acc_l[nt] = MFMA16(al, bfr, acc_l[nt]);
    }
  }
  // store transposed: st[col][row], rows kgrp*4..+3 contiguous -> float4
  #pragma unroll
  for(int nt=0; nt<2; nt++){
    int col = nt*16 + row16;
    float4 v;
    v.x = lrelu(acc_h[nt][0] + acc_l[nt][0] + sb1[col]);
    v.y = lrelu(acc_h[nt][1] + acc_l[nt][1] + sb1[col]);
    v.z = lrelu(acc_h[nt][2] + acc_l[nt][2] + sb1[col]);
    v.w = lrelu(acc_h[nt][3] + acc_l[nt][3] + sb1[col]);
    *(float4*)&myst[col*ST_STRIDE + kgrp*4] = v;
  }
  __syncthreads();

  // ---- GEMM2 + epilogue: each lane handles (r, h) and (r+8, h) ----
  int h = lane&7, r = lane>>3;
  float s0 = sb2[h], s1 = sb2[h];
  #pragma unroll 8
  for(int k=0;k<OUT_DIM;k++){
    float w = sw2f[k*NHEADS+h];
    s0 = fmaf(myst[k*ST_STRIDE + r],     w, s0);
    s1 = fmaf(myst[k*ST_STRIDE + r + 8], w, s1);
  }
  int ea0 = e0w + r, ea1 = e0w + r + 8;
  int sv0 = src[ea0], dv0 = dst[ea0];
  int sv1 = src[ea1], dv1 = dst[ea1];
  float av0 = lrelu(a1[sv0*NHEADS+h] + a2[dv0*NHEADS+h] + s0);   // TEMP==1
  float av1 = lrelu(a1[sv1*NHEADS+h] + a2[dv1*NHEADS+h] + s1);
  int pos0 = 0, pos1 = 0;
  if(h==0){
    pos0 = atomicAdd(&cursor[dv0], 1);
    pos1 = atomicAdd(&cursor[dv1], 1);
  }
  pos0 = __shfl(pos0, lane & 56, 64);
  pos1 = __shfl(pos1, lane & 56, 64);
  a_edge[(long)pos0*NHEADS + h] = av0;
  a_edge[(long)pos1*NHEADS + h] = av1;
  if(h==0){ psrc[pos0] = (unsigned short)sv0; psrc[pos1] = (unsigned short)sv1; }
  atomicMax(&amax[dv0*NHEADS+h], fenc(av0));
  atomicMax(&amax[dv1*NHEADS+h], fenc(av1));
}
__global__ __launch_bounds__(256) void k_edge_attn(const void* ein, const void* b1,
                                                   const void* w2, const void* b2,
                                                   const float* a1, const float* a2,
                                                   const int* src, const int* dst,
                                                   int* cursor, unsigned short* psrc,
                                                   float* a_edge, unsigned* amax,
                                                   const unsigned short* wpack, const int* flag){
  extern __shared__ float smemf[];
  if(*flag) edge_attn_body<true >(ein,b1,w2,b2,a1,a2,src,dst,cursor,psrc,a_edge,amax,wpack,smemf);
  else      edge_attn_body<false>(ein,b1,w2,b2,a1,a2,src,dst,cursor,psrc,a_edge,amax,wpack,smemf);
}

// ---------------- K4: fused CSR aggregation + softmax + residual + lrelu + BN stats --
// one wave per node; lane owns 4 consecutive columns (c = lane*4+k, head = lane>>3)
// -> one float4 gather per edge per lane.
template<bool F32> __device__ void agg_body(const int* rs, const unsigned short* psrc,
                                            const float* a_edge, const unsigned* amax,
                                            const float* ft, const void* xin, void* xout,
                                            double* dstats, double* sm){
  int wid = threadIdx.x>>6, lane = threadIdx.x&63;
  int gw = blockIdx.x*4 + wid, nw = gridDim.x*4;
  int h = lane>>3;                  // head of this lane's 4 columns
  double s4[4]={0,0,0,0}, q4[4]={0,0,0,0};
  for(int n=gw; n<N_NODES; n+=nw){
    int b0 = rs[n], b1 = rs[n+1];
    if(b1 > N_EDGES) b1 = N_EDGES;
    if(b0 > b1) b0 = b1;
    float m = (lane<8) ? fdec(amax[n*NHEADS+lane]) : 0.f;
    float zl = 0.f;
    float acc[4] = {0,0,0,0};
    for(int i=b0;i<b1;++i){
      float av = 0.f;
      if(lane<8){ av = __expf(a_edge[(long)i*NHEADS+lane] - m); zl += av; }
      int sv = psrc[i];
      float4 f = *(const float4*)(ft + (long)sv*HD + lane*4);
      float a = __shfl(av, h, 64);
      acc[0] = fmaf(a, f.x, acc[0]);
      acc[1] = fmaf(a, f.y, acc[1]);
      acc[2] = fmaf(a, f.z, acc[2]);
      acc[3] = fmaf(a, f.w, acc[3]);
    }
    float z = __shfl(zl, h, 64);
    float zs = (z==0.f) ? 1.f : z;
    #pragma unroll
    for(int q=0;q<4;q++){
      int c = lane*4 + q;
      float xv = lrelu(acc[q]/zs + LD<F32>(xin,(long)n*HD + c));
      ST<F32>(xout,(long)n*HD + c, xv);
      s4[q] += xv; q4[q] += (double)xv*(double)xv;
    }
  }
  double* ls = sm; double* lq = sm + 256;
  for(int w=0;w<4;w++){
    if(wid==w){
      #pragma unroll
      for(int q=0;q<4;q++){
        int c = lane*4 + q;
        if(w==0){ ls[c]=s4[q]; lq[c]=q4[q]; }
        else    { ls[c]+=s4[q]; lq[c]+=q4[q]; }
      }
    }
    __syncthreads();
  }
  int t = threadIdx.x;
  unsafeAtomicAdd(&dstats[t],    ls[t]);
  unsafeAtomicAdd(&dstats[HD+t], lq[t]);
}
__global__ __launch_bounds__(256) void k_agg(const int* rs, const unsigned short* psrc,
                                             const float* a_edge, const unsigned* amax,
                                             const float* ft, const void* xin, void* xout,
                                             double* dstats, const int* flag){
  extern __shared__ double smemd[];
  if(*flag) agg_body<true >(rs,psrc,a_edge,amax,ft,xin,xout,dstats,smemd);
  else      agg_body<false>(rs,psrc,a_edge,amax,ft,xin,xout,dstats,smemd);
}

// ---------------- BN params from double sums ----------------
template<bool F32> __device__ void bn_params_body(const double* dstats, const void* g,
                                                  const void* b, float* scsh, int C, double invM){
  int t = threadIdx.x;
  if(t>=C) return;
  double mu  = dstats[t]*invM;
  double var = dstats[C+t]*invM - mu*mu;
  if(var < 0.0) var = 0.0;
  float sc = LD<F32>(g,t) * rsqrtf((float)var + BN_EPS);
  scsh[t]   = sc;
  scsh[C+t] = LD<F32>(b,t) - (float)mu*sc;
}
__global__ void k_bn_params(const double* dstats, const void* g, const void* b,
                            float* scsh, int C, double invM, const int* flag){
  if(*flag) bn_params_body<true >(dstats,g,b,scsh,C,invM);
  else      bn_params_body<false>(dstats,g,b,scsh,C,invM);
}

// ---------------- K6c: fused node BN apply + P/Q = node_out @ Wn_top/Wn_bot ----------
// reads pre-BN x from d_out node section, applies y = x*sc+sh, writes y back in place
// (guarded: clamped tail threads never write), and computes P/Q from y via MFMA.
template<bool F32> __device__ void pq_body(void* nodex, const unsigned short* wpack,
                                           const float* scsh, float* P, float* Q){
  const uint4* wn4 = (const uint4*)wpack;
  int wid = threadIdx.x>>6, lane = threadIdx.x&63;
  int row16 = lane&15, kgrp = lane>>4;
  int r0 = blockIdx.x*64 + wid*16;
  bool owns = (r0 + row16) < N_NODES;
  long arow = owns ? (long)(r0 + row16) : (long)(N_NODES-1);
  f32x4 pacc[4], qacc[4];
  #pragma unroll
  for(int nt=0;nt<4;nt++){ pacc[nt]=(f32x4){0.f,0.f,0.f,0.f}; qacc[nt]=(f32x4){0.f,0.f,0.f,0.f}; }
  #pragma unroll 2
  for(int ks=0;ks<8;ks++){
    int cb = ks*32 + kgrp*8;
    float y[8];
    #pragma unroll
    for(int j=0;j<8;j++){
      float x = LD<F32>(nodex, arow*HD + cb + j);
      y[j] = fmaf(x, scsh[cb+j], scsh[HD+cb+j]);
    }
    bf16x8 ah, al;
    if constexpr(F32){
      float4 y0 = {y[0],y[1],y[2],y[3]}, y1 = {y[4],y[5],y[6],y[7]};
      split8(y0, y1, ah, al);
      if(owns){
        *(float4*)((float*)nodex + arow*HD + cb)     = y0;
        *(float4*)((float*)nodex + arow*HD + cb + 4) = y1;
      }
    } else {
      unsigned short us[8];
      #pragma unroll
      for(int j=0;j<8;j++){ union{bf16 h; unsigned short s;}u; u.h=f2b(y[j]); us[j]=u.s; }
      PackU pk;
      pk.u = make_uint4((unsigned)us[0]|((unsigned)us[1]<<16), (unsigned)us[2]|((unsigned)us[3]<<16),
                        (unsigned)us[4]|((unsigned)us[5]<<16), (unsigned)us[6]|((unsigned)us[7]<<16));
      ah = pk.v; al = zero_frag();
      if(owns) *(uint4*)((bf16*)nodex + arow*HD + cb) = pk.u;
    }
    const uint4* wbP = wn4 + (size_t)(ks*4)*64 + lane;
    const uint4* wbQ = wn4 + (size_t)((8+ks)*4)*64 + lane;
    #pragma unroll
    for(int nt=0;nt<4;nt++){
      bf16x8 bP = as_frag(wbP[nt*64]);
      bf16x8 bQ = as_frag(wbQ[nt*64]);
      pacc[nt] = MFMA16(ah, bP, pacc[nt]);
      qacc[nt] = MFMA16(ah, bQ, qacc[nt]);
      if constexpr(F32){
        pacc[nt] = MFMA16(al, bP, pacc[nt]);
        qacc[nt] = MFMA16(al, bQ, qacc[nt]);
      }
    }
  }
  #pragma unroll
  for(int nt=0;nt<4;nt++)
    #pragma unroll
    for(int j=0;j<4;j++){
      int r = r0 + kgrp*4 + j;
      if(r < N_NODES){
        P[(long)r*64 + nt*16 + row16] = pacc[nt][j];
        Q[(long)r*64 + nt*16 + row16] = qacc[nt][j];
      }
    }
}
__global__ __launch_bounds__(256) void k_pq(void* nodex, const unsigned short* wpack,
                                            const float* scsh, float* P, float* Q,
                                            const int* flag){
  if(*flag) pq_body<true >(nodex,wpack,scsh,P,Q);
  else      pq_body<false>(nodex,wpack,scsh,P,Q);
}

// ---------------- K7: fused edge update via MFMA (P/Q-factored) + edge BN stats -----
#define EF_LROW 68   // padded LDS row stride (f32) for the 16x64 per-wave ef tile

template<bool F32>
__device__ void edge_update_body(const float* P, const float* Q, const void* edge_in,
                                 const int* src, const int* dst,
                                 const unsigned short* wpack,
                                 void* d_out, double* dstats,
                                 float* lds, float* els, float* elq){
  void* edge_x = ESEC<F32>(d_out);
  const uint4* we4 = ((const uint4*)wpack) + 4096;
  const uint4* wf4 = ((const uint4*)wpack) + 4608;
  int tid   = threadIdx.x;
  int wid   = tid >> 6;
  int lane  = tid & 63;
  int row16 = lane & 15;
  int kgrp  = lane >> 4;
  int e0  = blockIdx.x*64 + wid*16;
  int e_a = e0 + row16;
  int nsrc = src[e_a], ndst = dst[e_a];
  float* myl = lds + wid*(16*EF_LROW);
  if(tid < 64){ els[tid] = 0.f; elq[tid] = 0.f; }

  f32x4 acc_h[4], acc_l[4];
  #pragma unroll
  for(int t=0;t<4;t++){ acc_h[t]=(f32x4){0.f,0.f,0.f,0.f}; acc_l[t]=(f32x4){0.f,0.f,0.f,0.f}; }

  // ---- ef GEMM: K = 64 ----
  long ebase = (long)e_a * EDGE_F;
  #pragma unroll
  for(int ks=0; ks<2; ks++){
    bf16x8 ah, al;
    load_split<F32>(edge_in, ebase + ks*32 + kgrp*8, ah, al);
    const uint4* wb = we4 + (size_t)(ks*4)*64 + lane;
    #pragma unroll
    for(int nt=0; nt<4; nt++){
      bf16x8 bfr = as_frag(wb[nt*64]);
      acc_h[nt] = MFMA16(ah, bfr, acc_h[nt]);
      if constexpr(F32) acc_l[nt] = MFMA16(al, bfr, acc_l[nt]);
    }
  }
  #pragma unroll
  for(int nt=0; nt<4; nt++)
    #pragma unroll
    for(int j=0;j<4;j++)
      myl[(kgrp*4+j)*EF_LROW + nt*16 + row16] = lrelu(acc_h[nt][j] + acc_l[nt][j]);

  __syncthreads();   // ef C-layout -> A-layout redistribution (also covers els/elq init)

  // ---- final GEMM: K = 128 (k 0..63 = nf from P/Q gather, k 64..127 = ef from LDS) ----
  #pragma unroll
  for(int t=0;t<4;t++){ acc_h[t]=(f32x4){0.f,0.f,0.f,0.f}; acc_l[t]=(f32x4){0.f,0.f,0.f,0.f}; }
  #pragma unroll
  for(int ks=0; ks<2; ks++){
    const float* pp = P + (long)nsrc*64 + ks*32 + kgrp*8;
    const float* qq = Q + (long)ndst*64 + ks*32 + kgrp*8;
    float4 p0 = *(const float4*)pp, p1 = *(const float4*)(pp+4);
    float4 q0 = *(const float4*)qq, q1 = *(const float4*)(qq+4);
    float4 v0, v1;
    v0.x = lrelu(p0.x+q0.x); v0.y = lrelu(p0.y+q0.y);
    v0.z = lrelu(p0.z+q0.z); v0.w = lrelu(p0.w+q0.w);
    v1.x = lrelu(p1.x+q1.x); v1.y = lrelu(p1.y+q1.y);
    v1.z = lrelu(p1.z+q1.z); v1.w = lrelu(p1.w+q1.w);
    bf16x8 ah, al; split8(v0, v1, ah, al);
    const uint4* wb = wf4 + (size_t)(ks*4)*64 + lane;
    #pragma unroll
    for(int nt=0; nt<4; nt++){
      bf16x8 bfr = as_frag(wb[nt*64]);
      acc_h[nt] = MFMA16(ah, bfr, acc_h[nt]);
      acc_l[nt] = MFMA16(al, bfr, acc_l[nt]);
    }
  }
  #pragma unroll
  for(int ks=2; ks<4; ks++){
    const float* ap = myl + row16*EF_LROW + (ks-2)*32 + kgrp*8;
    float4 a0 = *(const float4*)ap;
    float4 a1 = *(const float4*)(ap+4);
    bf16x8 ah, al; split8(a0, a1, ah, al);
    const uint4* wb = wf4 + (size_t)(ks*4)*64 + lane;
    #pragma unroll
    for(int nt=0; nt<4; nt++){
      bf16x8 bfr = as_frag(wb[nt*64]);
      acc_h[nt] = MFMA16(ah, bfr, acc_h[nt]);
      acc_l[nt] = MFMA16(al, bfr, acc_l[nt]);
    }
  }
  #pragma unroll
  for(int nt=0; nt<4; nt++){
    float ssum = 0.f, qsum = 0.f;
    #pragma unroll
    for(int j=0;j<4;j++){
      long e = e0 + kgrp*4 + j;
      int  c = nt*16 + row16;
      float res = LD<F32>(edge_in, e*EDGE_OUT + c);
      float v = lrelu(acc_h[nt][j] + acc_l[nt][j] + res);
      ST<F32>(edge_x, e*EDGE_OUT + c, v);
      ssum += v; qsum += v*v;
    }
    atomicAdd(&els[nt*16+row16], ssum);
    atomicAdd(&elq[nt*16+row16], qsum);
  }
  __syncthreads();
  if(tid < 64){
    unsafeAtomicAdd(&dstats[tid],    (double)els[tid]);
    unsafeAtomicAdd(&dstats[64+tid], (double)elq[tid]);
  }
}
__global__ __launch_bounds__(256) void k_edge_update(const float* P, const float* Q,
                                                     const void* edge_in,
                                                     const int* src, const int* dst,
                                                     const unsigned short* wpack,
                                                     void* d_out, double* dstats,
                                                     const int* flag){
  extern __shared__ float smemf[];
  __shared__ float els[64], elq[64];
  if(*flag) edge_update_body<true >(P,Q,edge_in,src,dst,wpack,d_out,dstats,smemf,els,elq);
  else      edge_update_body<false>(P,Q,edge_in,src,dst,wpack,d_out,dstats,smemf,els,elq);
}

// ---------------- K9: edge BN apply, in place on d_out edge section ----------------
template<bool F32> __device__ void edge_apply_body(void* d_out, const float* scsh){
  void* ex = ESEC<F32>(d_out);
  int t = threadIdx.x;
  int c = t & 63;
  float sc = scsh[c], sh = scsh[64+c];
  for(long i=(long)blockIdx.x*256+t; i<(long)N_EDGES*EDGE_OUT; i+=(long)gridDim.x*256){
    ST<F32>(ex, i, fmaf(LD<F32>(ex,i), sc, sh));
  }
}
__global__ __launch_bounds__(256) void k_edge_apply(void* d_out, const float* scsh, const int* flag){
  if(*flag) edge_apply_body<true >(d_out,scsh);
  else      edge_apply_body<false>(d_out,scsh);
}

extern "C" void kernel_launch(void* const* d_in, const int* in_sizes, int n_in,
                              void* d_out, int out_size, void* d_ws, size_t ws_size,
                              hipStream_t stream){
  const void* node_in    = d_in[0];
  const void* edge_in    = d_in[1];
  const void* fc_w       = d_in[2];
  const void* attn_l     = d_in[3];
  const void* attn_r     = d_in[4];
  const void* ae_w1      = d_in[5];
  const void* ae_b1      = d_in[6];
  const void* ae_w2      = d_in[7];
  const void* ae_b2      = d_in[8];
  const void* bn_n_g     = d_in[9];
  const void* bn_n_b     = d_in[10];
  const void* eu_node_w  = d_in[11];
  const void* eu_edge_w  = d_in[12];
  const void* eu_final_w = d_in[13];
  const void* bn_e_g     = d_in[14];
  const void* bn_e_b     = d_in[15];
  const int*  src        = (const int*)d_in[16];
  const int*  dst        = (const int*)d_in[17];

  // ---- workspace, all inside d_ws (~70.28 MB total; proven envelope >= 70.41 MB) ----
  char* base = (char*)d_ws;
  double*   dstats_n = (double*)base;                 // 512 dbl
  double*   dstats_e = (double*)(base + 4096);        // 128 dbl
  float*    scsh_n   = (float*)(base + 5120);         // 512 f
  float*    scsh_e   = (float*)(base + 7168);         // 128 f
  int*      flag     = (int*)(base + 7680);
  char*     big      = base + 8192;
  float*    ftb      = (float*)big;                   // N*HD f32 = 51.2MB (always f32)
  float*    Pb       = (float*)big;                   // N*64 f32 = 12.8MB (reuses ftb after k_agg)
  float*    Qb       = (float*)(big + 12800000);      // N*64 f32 = 12.8MB
  float*    a_edge   = (float*)(big + 51200000);      // E*8 f32 (CSR order) = 12.8MB
  float*    a1       = (float*)(big + 64000000);      // N*8 f32
  float*    a2       = (float*)(big + 65600000);      // N*8 f32
  unsigned* amax     = (unsigned*)(big + 67200000);   // N*8 u32 -> ends 68.8MB
  unsigned short* wpack_eu = (unsigned short*)(big + 68800000);  // 94.2KB (incl. aw1)
  unsigned short* wpack_fc = (unsigned short*)(big + 68900000);  // 128KB
  int*      rsb      = (int*)(big + 69040000);        // NBINS ints (202KB)
  int*      cursor   = (int*)(big + 69250000);        // NBINS ints (doubles as histogram)
  int*      btot     = (int*)(big + 69460000);        // NBLK ints
  int*      bsum     = (int*)(big + 69461024);        // NBLK ints
  unsigned short* psrc = (unsigned short*)(big + 69470000); // E u16 (0.8MB) -> ends 70.27MB

  hipMemsetAsync(dstats_n, 0, 640*sizeof(double), stream);
  hipMemsetAsync(amax, 0, (size_t)N_NODES*NHEADS*sizeof(unsigned), stream);
  hipMemsetAsync(cursor, 0, NBINS*sizeof(int), stream);

  k_detect<<<1, 256, 0, stream>>>((const unsigned short*)node_in, flag);
  // CSR build (flag-independent)
  k_hist <<<(N_EDGES+255)/256, 256, 0, stream>>>(dst, cursor);
  k_scan1<<<NBLK, 256, 0, stream>>>(cursor, rsb, btot);
  k_scan2<<<1, 256, 0, stream>>>(btot, bsum);
  k_scan3<<<NBLK, 256, 0, stream>>>(rsb, bsum, cursor);
  // weight packs
  k_pack_fc<<<256, 256, 0, stream>>>(fc_w, wpack_fc, flag);
  k_pack_w<<<184, 256, 0, stream>>>(eu_node_w, eu_edge_w, eu_final_w, ae_w1, wpack_eu, flag);
  // node projection (MFMA) + attention scalars
  k_node_proj<<<(N_NODES+63)/64, 256, 0, stream>>>(node_in, wpack_fc, ftb, flag);
  k_attn<<<N_NODES*NHEADS/8, 256, 0, stream>>>(ftb, attn_l, attn_r, a1, a2, flag);
  // edge attention (MFMA) -> CSR slots + segment max
  k_edge_attn<<<N_EDGES/64, 256, (296 + 4*32*ST_STRIDE)*4, stream>>>(
      edge_in, ae_b1, ae_w2, ae_b2, a1, a2, src, dst, cursor, psrc,
      a_edge, amax, wpack_eu, flag);
  // fused softmax + aggregation + residual + lrelu + BN stats (float4 gather, full occupancy)
  k_agg<<<2048, 256, 4096, stream>>>(rsb, psrc, a_edge, amax, ftb, node_in, d_out,
                                     dstats_n, flag);
  k_bn_params<<<1, 256, 0, stream>>>(dstats_n, bn_n_g, bn_n_b, scsh_n, HD, 1.0/N_NODES, flag);
  // fused node BN apply + P/Q projection (ftb dead after k_agg; reuse its space)
  k_pq<<<(N_NODES+63)/64, 256, 0, stream>>>(d_out, wpack_eu, scsh_n, Pb, Qb, flag);
  // edge update (MFMA, P/Q-factored, fused BN stats) + BN
  k_edge_update<<<N_EDGES/64, 256, 4*16*EF_LROW*4, stream>>>(Pb, Qb, edge_in, src, dst,
                                                             wpack_eu, d_out, dstats_e, flag);
  k_bn_params<<<1, 256, 0, stream>>>(dstats_e, bn_e_g, bn_e_b, scsh_e, EDGE_OUT, 1.0/N_EDGES, flag);
  k_edge_apply<<<2048, 256, 0, stream>>>(d_out, scsh_e, flag);
  (void)ws_size; (void)out_size; (void)n_in; (void)in_sizes;
}